// Round 1
// baseline (8758.352 us; speedup 1.0000x reference)
//
#include <hip/hip_runtime.h>
#include <math.h>

#define N_NODES 100000
#define N_EDGES 1600000
#define D 128
#define DOUT 64
#define EPS 1e-5f

// ---------------- degree ----------------
__global__ __launch_bounds__(256) void k_deg(const int* __restrict__ dst,
                                             int* __restrict__ deg) {
    int e = blockIdx.x * 256 + threadIdx.x;
    if (e < N_EDGES) atomicAdd(&deg[dst[e]], 1);
}

__global__ __launch_bounds__(256) void k_invdeg(const int* __restrict__ deg,
                                                float* __restrict__ invdeg) {
    int i = blockIdx.x * 256 + threadIdx.x;
    if (i < N_NODES) invdeg[i] = 1.0f / fmaxf((float)deg[i], 1.0f);
}

// ---------------- scatter-add aggregation ----------------
// tid -> (edge, float4-chunk). 32 consecutive threads cover one edge's 128 floats.
__global__ __launch_bounds__(256) void k_scatter(const float* __restrict__ h,
                                                 const int* __restrict__ src,
                                                 const int* __restrict__ dst,
                                                 float* __restrict__ agg) {
    int tid = blockIdx.x * 256 + threadIdx.x;   // < E*32 = 51.2M
    int e = tid >> 5;
    int c = tid & 31;
    int s = src[e];
    int d = dst[e];
    float4 v = ((const float4*)h)[s * 32 + c];
    float* base = &agg[d * 128 + c * 4];
    unsafeAtomicAdd(base + 0, v.x);
    unsafeAtomicAdd(base + 1, v.y);
    unsafeAtomicAdd(base + 2, v.z);
    unsafeAtomicAdd(base + 3, v.w);
}

// ---------------- fused dual-GEMM + bias + LayerNorm + ReLU (d=128 -> 128) ----
// Block: 256 threads, 32 rows/block. Thread = (cgrp = tid&31 -> 4 cols,
// rgrp = tid>>5 -> 4 rows). LDS: h rows, scaled agg rows, Wr/Wn 32-k tiles.
__global__ __launch_bounds__(256) void k_gemm_ln(
        const float* __restrict__ h, const float* __restrict__ agg,
        const float* __restrict__ invdeg,
        const float* __restrict__ Wr, const float* __restrict__ Wn,
        const float* __restrict__ b, const float* __restrict__ g,
        const float* __restrict__ be, float* __restrict__ out) {
    __shared__ float hl[32][128];
    __shared__ float al[32][128];
    __shared__ float wrl[32][128];
    __shared__ float wnl[32][128];

    const int tid = threadIdx.x;
    const int row0 = blockIdx.x * 32;           // N divisible by 32? 100000/32=3125 exact
    const int cgrp = tid & 31;                  // float4 column group
    const int c0 = cgrp * 4;
    const int r0 = (tid >> 5) * 4;              // 8 row groups * 4 rows

    // stage h and invdeg-scaled agg rows (1024 float4 per array, 4 per thread)
    #pragma unroll
    for (int t = 0; t < 4; ++t) {
        int i = tid + t * 256;
        int r = i >> 5;
        int c4 = i & 31;
        int grow = row0 + r;
        ((float4*)&hl[r][0])[c4] = ((const float4*)h)[grow * 32 + c4];
        float4 av = ((const float4*)agg)[grow * 32 + c4];
        float id = invdeg[grow];
        av.x *= id; av.y *= id; av.z *= id; av.w *= id;
        ((float4*)&al[r][0])[c4] = av;
    }

    float acc[4][4];
    #pragma unroll
    for (int r = 0; r < 4; ++r)
        #pragma unroll
        for (int c = 0; c < 4; ++c) acc[r][c] = 0.0f;

    for (int kt = 0; kt < 4; ++kt) {
        __syncthreads();   // covers h/agg staging (kt=0) and protects W tiles
        #pragma unroll
        for (int t = 0; t < 4; ++t) {
            int i = tid + t * 256;
            int r = i >> 5;
            int c4 = i & 31;
            ((float4*)&wrl[r][0])[c4] = ((const float4*)Wr)[(kt * 32 + r) * 32 + c4];
            ((float4*)&wnl[r][0])[c4] = ((const float4*)Wn)[(kt * 32 + r) * 32 + c4];
        }
        __syncthreads();
        #pragma unroll
        for (int k = 0; k < 32; ++k) {
            float4 wr = *(const float4*)&wrl[k][c0];
            float4 wn = *(const float4*)&wnl[k][c0];
            int kk = kt * 32 + k;
            #pragma unroll
            for (int r = 0; r < 4; ++r) {
                float hh = hl[r0 + r][kk];
                float aa = al[r0 + r][kk];
                acc[r][0] = fmaf(hh, wr.x, acc[r][0]);
                acc[r][1] = fmaf(hh, wr.y, acc[r][1]);
                acc[r][2] = fmaf(hh, wr.z, acc[r][2]);
                acc[r][3] = fmaf(hh, wr.w, acc[r][3]);
                acc[r][0] = fmaf(aa, wn.x, acc[r][0]);
                acc[r][1] = fmaf(aa, wn.y, acc[r][1]);
                acc[r][2] = fmaf(aa, wn.z, acc[r][2]);
                acc[r][3] = fmaf(aa, wn.w, acc[r][3]);
            }
        }
    }

    // epilogue: + bias, LayerNorm over 128 cols (32 lanes * 4 vals), ReLU
    float4 bv = ((const float4*)b)[cgrp];
    float4 gv = ((const float4*)g)[cgrp];
    float4 bev = ((const float4*)be)[cgrp];
    #pragma unroll
    for (int r = 0; r < 4; ++r) {
        float v0 = acc[r][0] + bv.x;
        float v1 = acc[r][1] + bv.y;
        float v2 = acc[r][2] + bv.z;
        float v3 = acc[r][3] + bv.w;
        float s1 = v0 + v1 + v2 + v3;
        float s2 = v0 * v0 + v1 * v1 + v2 * v2 + v3 * v3;
        #pragma unroll
        for (int m = 16; m >= 1; m >>= 1) {
            s1 += __shfl_xor(s1, m);
            s2 += __shfl_xor(s2, m);
        }
        float mean = s1 * (1.0f / 128.0f);
        float var = s2 * (1.0f / 128.0f) - mean * mean;
        float rstd = rsqrtf(var + EPS);
        float4 o;
        o.x = fmaxf((v0 - mean) * rstd * gv.x + bev.x, 0.0f);
        o.y = fmaxf((v1 - mean) * rstd * gv.y + bev.y, 0.0f);
        o.z = fmaxf((v2 - mean) * rstd * gv.z + bev.z, 0.0f);
        o.w = fmaxf((v3 - mean) * rstd * gv.w + bev.w, 0.0f);
        ((float4*)out)[(row0 + r0 + r) * 32 + cgrp] = o;
    }
}

// ---------------- layer 2: dual-GEMM (128 -> 64) + bias + log_softmax -------
// Block: 256 threads = 4 rows x 64 cols. One wave per row -> shuffle reduce.
__global__ __launch_bounds__(256) void k_l2(
        const float* __restrict__ h, const float* __restrict__ agg,
        const float* __restrict__ invdeg,
        const float* __restrict__ Wr, const float* __restrict__ Wn,
        const float* __restrict__ b, float* __restrict__ out) {
    __shared__ float hl[4][128];
    __shared__ float al[4][128];
    const int tid = threadIdx.x;
    const int row0 = blockIdx.x * 4;            // 100000/4 = 25000 exact

    int i = tid & 127;
    int r = i >> 5;
    int c4 = i & 31;
    if (tid < 128) {
        ((float4*)&hl[r][0])[c4] = ((const float4*)h)[(row0 + r) * 32 + c4];
    } else {
        float4 av = ((const float4*)agg)[(row0 + r) * 32 + c4];
        float id = invdeg[row0 + r];
        av.x *= id; av.y *= id; av.z *= id; av.w *= id;
        ((float4*)&al[r][0])[c4] = av;
    }
    __syncthreads();

    const int j = tid & 63;
    const int rr = tid >> 6;
    float acc = b[j];
    #pragma unroll 8
    for (int k = 0; k < 128; ++k) {
        acc = fmaf(hl[rr][k], Wr[k * 64 + j], acc);
        acc = fmaf(al[rr][k], Wn[k * 64 + j], acc);
    }

    // log_softmax over 64 classes (full wave)
    float m = acc;
    #pragma unroll
    for (int msk = 32; msk >= 1; msk >>= 1) m = fmaxf(m, __shfl_xor(m, msk));
    float e = __expf(acc - m);
    float s = e;
    #pragma unroll
    for (int msk = 32; msk >= 1; msk >>= 1) s += __shfl_xor(s, msk);
    out[(row0 + rr) * 64 + j] = acc - m - logf(s);
}

extern "C" void kernel_launch(void* const* d_in, const int* in_sizes, int n_in,
                              void* d_out, int out_size, void* d_ws, size_t ws_size,
                              hipStream_t stream) {
    const float* x   = (const float*)d_in[0];
    const int* esrc  = (const int*)d_in[1];
    const int* edst  = (const int*)d_in[2];
    const float* Wr0 = (const float*)d_in[3];
    const float* Wn0 = (const float*)d_in[4];
    const float* b0  = (const float*)d_in[5];
    const float* g0  = (const float*)d_in[6];
    const float* be0 = (const float*)d_in[7];
    const float* Wr1 = (const float*)d_in[8];
    const float* Wn1 = (const float*)d_in[9];
    const float* b1  = (const float*)d_in[10];
    const float* g1  = (const float*)d_in[11];
    const float* be1 = (const float*)d_in[12];
    const float* Wr2 = (const float*)d_in[13];
    const float* Wn2 = (const float*)d_in[14];
    const float* b2  = (const float*)d_in[15];
    float* out = (float*)d_out;

    // workspace layout (~104 MB): deg | invdeg | A (agg) | B (hidden)
    char* ws = (char*)d_ws;
    int*   deg    = (int*)ws;                                   // 400 KB
    float* invdeg = (float*)(ws + 0x80000);                     // 400 KB
    float* A      = (float*)(ws + 0x100000);                    // 51.2 MB
    float* B      = (float*)(ws + 0x100000 + (size_t)N_NODES * 128 * 4);

    const size_t aggBytes = (size_t)N_NODES * 128 * 4;
    const int scatterBlocks = N_EDGES * 32 / 256;               // 200000

    hipMemsetAsync(deg, 0, N_NODES * sizeof(int), stream);
    hipMemsetAsync(A, 0, aggBytes, stream);
    k_deg<<<(N_EDGES + 255) / 256, 256, 0, stream>>>(edst, deg);
    k_invdeg<<<(N_NODES + 255) / 256, 256, 0, stream>>>(deg, invdeg);

    // layer 0
    k_scatter<<<scatterBlocks, 256, 0, stream>>>(x, esrc, edst, A);
    k_gemm_ln<<<N_NODES / 32, 256, 0, stream>>>(x, A, invdeg, Wr0, Wn0, b0, g0, be0, B);

    // layer 1 (in-place on B: each block only touches its own 32 rows)
    hipMemsetAsync(A, 0, aggBytes, stream);
    k_scatter<<<scatterBlocks, 256, 0, stream>>>(B, esrc, edst, A);
    k_gemm_ln<<<N_NODES / 32, 256, 0, stream>>>(B, A, invdeg, Wr1, Wn1, b1, g1, be1, B);

    // layer 2 + log_softmax
    hipMemsetAsync(A, 0, aggBytes, stream);
    k_scatter<<<scatterBlocks, 256, 0, stream>>>(B, esrc, edst, A);
    k_l2<<<N_NODES / 4, 256, 0, stream>>>(B, A, invdeg, Wr2, Wn2, b2, out);
}

// Round 2
// 1143.465 us; speedup vs baseline: 7.6595x; 7.6595x over previous
//
#include <hip/hip_runtime.h>
#include <math.h>

#define N_NODES 100000
#define N_EDGES 1600000
#define EPS 1e-5f
#define NB 391              // ceil(100000/256) scan blocks

// ---------------- degree ----------------
__global__ __launch_bounds__(256) void k_deg(const int* __restrict__ dst,
                                             int* __restrict__ deg) {
    int e = blockIdx.x * 256 + threadIdx.x;
    if (e < N_EDGES) atomicAdd(&deg[dst[e]], 1);
}

__global__ __launch_bounds__(256) void k_invdeg(const int* __restrict__ deg,
                                                float* __restrict__ invdeg) {
    int i = blockIdx.x * 256 + threadIdx.x;
    if (i < N_NODES) invdeg[i] = 1.0f / fmaxf((float)deg[i], 1.0f);
}

// ---------------- CSR build: 3-kernel exclusive scan + fill ----------------
__global__ __launch_bounds__(256) void k_scan1(const int* __restrict__ deg,
                                               int* __restrict__ rowptr,
                                               int* __restrict__ bsum) {
    __shared__ int tmp[256];
    int t = threadIdx.x;
    int i = blockIdx.x * 256 + t;
    int v = (i < N_NODES) ? deg[i] : 0;
    tmp[t] = v;
    __syncthreads();
    #pragma unroll
    for (int off = 1; off < 256; off <<= 1) {
        int y = 0;
        if (t >= off) y = tmp[t - off];
        __syncthreads();
        if (t >= off) tmp[t] += y;
        __syncthreads();
    }
    if (i < N_NODES) rowptr[i] = tmp[t] - v;   // exclusive within block
    if (t == 255) bsum[blockIdx.x] = tmp[t];
}

__global__ __launch_bounds__(512) void k_scan2(int* __restrict__ bsum) {
    __shared__ int tmp[512];
    int t = threadIdx.x;
    int v = (t < NB) ? bsum[t] : 0;
    tmp[t] = v;
    __syncthreads();
    #pragma unroll
    for (int off = 1; off < 512; off <<= 1) {
        int y = 0;
        if (t >= off) y = tmp[t - off];
        __syncthreads();
        if (t >= off) tmp[t] += y;
        __syncthreads();
    }
    if (t < NB) bsum[t] = tmp[t] - v;          // exclusive block offsets
}

__global__ __launch_bounds__(256) void k_scan3(int* __restrict__ rowptr,
                                               int* __restrict__ cursor,
                                               const int* __restrict__ bsum) {
    int i = blockIdx.x * 256 + threadIdx.x;
    if (i < N_NODES) {
        int r = rowptr[i] + bsum[blockIdx.x];
        rowptr[i] = r;
        cursor[i] = r;
    }
}

__global__ __launch_bounds__(256) void k_fill(const int* __restrict__ src,
                                              const int* __restrict__ dst,
                                              int* __restrict__ cursor,
                                              int* __restrict__ eidx) {
    int e = blockIdx.x * 256 + threadIdx.x;
    if (e < N_EDGES) {
        int p = atomicAdd(&cursor[dst[e]], 1);
        eidx[p] = src[e];
    }
}

// ---------------- gather mean-aggregation: one wave per node ----------------
__global__ __launch_bounds__(256) void k_gather(const float* __restrict__ h,
                                                const int* __restrict__ eidx,
                                                const int* __restrict__ rowptr,
                                                const int* __restrict__ deg,
                                                const float* __restrict__ invdeg,
                                                float* __restrict__ agg) {
    int node = blockIdx.x * 4 + (threadIdx.x >> 6);     // 25000 blocks * 4 waves
    int lane = threadIdx.x & 63;
    int start = rowptr[node];
    int cnt = deg[node];
    float ax = 0.0f, ay = 0.0f;
    int j = 0;
    for (; j + 2 <= cnt; j += 2) {
        int s0 = eidx[start + j];
        int s1 = eidx[start + j + 1];
        float2 v0 = ((const float2*)h)[s0 * 64 + lane];
        float2 v1 = ((const float2*)h)[s1 * 64 + lane];
        ax += v0.x + v1.x;
        ay += v0.y + v1.y;
    }
    if (j < cnt) {
        int s0 = eidx[start + j];
        float2 v0 = ((const float2*)h)[s0 * 64 + lane];
        ax += v0.x;
        ay += v0.y;
    }
    float id = invdeg[node];
    float2 o;
    o.x = ax * id;
    o.y = ay * id;
    ((float2*)agg)[node * 64 + lane] = o;
}

// ---------------- fused dual-GEMM + bias + LayerNorm + ReLU (128 -> 128) ----
// agg is already the mean (invdeg folded into gather).
__global__ __launch_bounds__(256) void k_gemm_ln(
        const float* __restrict__ h, const float* __restrict__ agg,
        const float* __restrict__ Wr, const float* __restrict__ Wn,
        const float* __restrict__ b, const float* __restrict__ g,
        const float* __restrict__ be, float* __restrict__ out) {
    __shared__ float hl[32][128];
    __shared__ float al[32][128];
    __shared__ float wrl[32][128];
    __shared__ float wnl[32][128];

    const int tid = threadIdx.x;
    const int row0 = blockIdx.x * 32;
    const int cgrp = tid & 31;
    const int c0 = cgrp * 4;
    const int r0 = (tid >> 5) * 4;

    #pragma unroll
    for (int t = 0; t < 4; ++t) {
        int i = tid + t * 256;
        int r = i >> 5;
        int c4 = i & 31;
        int grow = row0 + r;
        ((float4*)&hl[r][0])[c4] = ((const float4*)h)[grow * 32 + c4];
        ((float4*)&al[r][0])[c4] = ((const float4*)agg)[grow * 32 + c4];
    }

    float acc[4][4];
    #pragma unroll
    for (int r = 0; r < 4; ++r)
        #pragma unroll
        for (int c = 0; c < 4; ++c) acc[r][c] = 0.0f;

    for (int kt = 0; kt < 4; ++kt) {
        __syncthreads();
        #pragma unroll
        for (int t = 0; t < 4; ++t) {
            int i = tid + t * 256;
            int r = i >> 5;
            int c4 = i & 31;
            ((float4*)&wrl[r][0])[c4] = ((const float4*)Wr)[(kt * 32 + r) * 32 + c4];
            ((float4*)&wnl[r][0])[c4] = ((const float4*)Wn)[(kt * 32 + r) * 32 + c4];
        }
        __syncthreads();
        #pragma unroll
        for (int k = 0; k < 32; ++k) {
            float4 wr = *(const float4*)&wrl[k][c0];
            float4 wn = *(const float4*)&wnl[k][c0];
            int kk = kt * 32 + k;
            #pragma unroll
            for (int r = 0; r < 4; ++r) {
                float hh = hl[r0 + r][kk];
                float aa = al[r0 + r][kk];
                acc[r][0] = fmaf(hh, wr.x, acc[r][0]);
                acc[r][1] = fmaf(hh, wr.y, acc[r][1]);
                acc[r][2] = fmaf(hh, wr.z, acc[r][2]);
                acc[r][3] = fmaf(hh, wr.w, acc[r][3]);
                acc[r][0] = fmaf(aa, wn.x, acc[r][0]);
                acc[r][1] = fmaf(aa, wn.y, acc[r][1]);
                acc[r][2] = fmaf(aa, wn.z, acc[r][2]);
                acc[r][3] = fmaf(aa, wn.w, acc[r][3]);
            }
        }
    }

    float4 bv = ((const float4*)b)[cgrp];
    float4 gv = ((const float4*)g)[cgrp];
    float4 bev = ((const float4*)be)[cgrp];
    #pragma unroll
    for (int r = 0; r < 4; ++r) {
        float v0 = acc[r][0] + bv.x;
        float v1 = acc[r][1] + bv.y;
        float v2 = acc[r][2] + bv.z;
        float v3 = acc[r][3] + bv.w;
        float s1 = v0 + v1 + v2 + v3;
        float s2 = v0 * v0 + v1 * v1 + v2 * v2 + v3 * v3;
        #pragma unroll
        for (int m = 16; m >= 1; m >>= 1) {
            s1 += __shfl_xor(s1, m);
            s2 += __shfl_xor(s2, m);
        }
        float mean = s1 * (1.0f / 128.0f);
        float var = s2 * (1.0f / 128.0f) - mean * mean;
        float rstd = rsqrtf(var + EPS);
        float4 o;
        o.x = fmaxf((v0 - mean) * rstd * gv.x + bev.x, 0.0f);
        o.y = fmaxf((v1 - mean) * rstd * gv.y + bev.y, 0.0f);
        o.z = fmaxf((v2 - mean) * rstd * gv.z + bev.z, 0.0f);
        o.w = fmaxf((v3 - mean) * rstd * gv.w + bev.w, 0.0f);
        ((float4*)out)[(row0 + r0 + r) * 32 + cgrp] = o;
    }
}

// ---------------- layer 2: dual-GEMM (128 -> 64) + bias + log_softmax -------
__global__ __launch_bounds__(256) void k_l2(
        const float* __restrict__ h, const float* __restrict__ agg,
        const float* __restrict__ Wr, const float* __restrict__ Wn,
        const float* __restrict__ b, float* __restrict__ out) {
    __shared__ float hl[4][128];
    __shared__ float al[4][128];
    const int tid = threadIdx.x;
    const int row0 = blockIdx.x * 4;

    int i = tid & 127;
    int r = i >> 5;
    int c4 = i & 31;
    if (tid < 128) {
        ((float4*)&hl[r][0])[c4] = ((const float4*)h)[(row0 + r) * 32 + c4];
    } else {
        ((float4*)&al[r][0])[c4] = ((const float4*)agg)[(row0 + r) * 32 + c4];
    }
    __syncthreads();

    const int j = tid & 63;
    const int rr = tid >> 6;
    float acc = b[j];
    #pragma unroll 8
    for (int k = 0; k < 128; ++k) {
        acc = fmaf(hl[rr][k], Wr[k * 64 + j], acc);
        acc = fmaf(al[rr][k], Wn[k * 64 + j], acc);
    }

    float m = acc;
    #pragma unroll
    for (int msk = 32; msk >= 1; msk >>= 1) m = fmaxf(m, __shfl_xor(m, msk));
    float e = __expf(acc - m);
    float s = e;
    #pragma unroll
    for (int msk = 32; msk >= 1; msk >>= 1) s += __shfl_xor(s, msk);
    out[(row0 + rr) * 64 + j] = acc - m - logf(s);
}

extern "C" void kernel_launch(void* const* d_in, const int* in_sizes, int n_in,
                              void* d_out, int out_size, void* d_ws, size_t ws_size,
                              hipStream_t stream) {
    const float* x   = (const float*)d_in[0];
    const int* esrc  = (const int*)d_in[1];
    const int* edst  = (const int*)d_in[2];
    const float* Wr0 = (const float*)d_in[3];
    const float* Wn0 = (const float*)d_in[4];
    const float* b0  = (const float*)d_in[5];
    const float* g0  = (const float*)d_in[6];
    const float* be0 = (const float*)d_in[7];
    const float* Wr1 = (const float*)d_in[8];
    const float* Wn1 = (const float*)d_in[9];
    const float* b1  = (const float*)d_in[10];
    const float* g1  = (const float*)d_in[11];
    const float* be1 = (const float*)d_in[12];
    const float* Wr2 = (const float*)d_in[13];
    const float* Wn2 = (const float*)d_in[14];
    const float* b2  = (const float*)d_in[15];
    float* out = (float*)d_out;

    // workspace layout
    char* p = (char*)d_ws;
    auto alloc = [&](size_t bytes) {
        void* r = (void*)p;
        p += (bytes + 255) & ~(size_t)255;
        return r;
    };
    int*   deg    = (int*)  alloc(N_NODES * 4);
    float* invdeg = (float*)alloc(N_NODES * 4);
    int*   rowptr = (int*)  alloc(N_NODES * 4);
    int*   cursor = (int*)  alloc(N_NODES * 4);
    int*   bsum   = (int*)  alloc(NB * 4);
    int*   eidx   = (int*)  alloc((size_t)N_EDGES * 4);
    float* A      = (float*)alloc((size_t)N_NODES * 128 * 4);
    float* B      = (float*)alloc((size_t)N_NODES * 128 * 4);

    // ---- build CSR (per call; ws is re-poisoned every launch) ----
    hipMemsetAsync(deg, 0, N_NODES * sizeof(int), stream);
    k_deg<<<(N_EDGES + 255) / 256, 256, 0, stream>>>(edst, deg);
    k_invdeg<<<NB, 256, 0, stream>>>(deg, invdeg);
    k_scan1<<<NB, 256, 0, stream>>>(deg, rowptr, bsum);
    k_scan2<<<1, 512, 0, stream>>>(bsum);
    k_scan3<<<NB, 256, 0, stream>>>(rowptr, cursor, bsum);
    k_fill<<<(N_EDGES + 255) / 256, 256, 0, stream>>>(esrc, edst, cursor, eidx);

    // layer 0
    k_gather<<<N_NODES / 4, 256, 0, stream>>>(x, eidx, rowptr, deg, invdeg, A);
    k_gemm_ln<<<N_NODES / 32, 256, 0, stream>>>(x, A, Wr0, Wn0, b0, g0, be0, B);

    // layer 1
    k_gather<<<N_NODES / 4, 256, 0, stream>>>(B, eidx, rowptr, deg, invdeg, A);
    k_gemm_ln<<<N_NODES / 32, 256, 0, stream>>>(B, A, Wr1, Wn1, b1, g1, be1, B);

    // layer 2 + log_softmax
    k_gather<<<N_NODES / 4, 256, 0, stream>>>(B, eidx, rowptr, deg, invdeg, A);
    k_l2<<<N_NODES / 4, 256, 0, stream>>>(B, A, Wr2, Wn2, b2, out);
}

// Round 3
// 605.253 us; speedup vs baseline: 14.4706x; 1.8892x over previous
//
#include <hip/hip_runtime.h>
#include <math.h>

#define N_NODES 100000
#define N_EDGES 1600000
#define EPS 1e-5f
#define NB 391              // ceil(100000/256) scan blocks

typedef __bf16 bf16x8 __attribute__((ext_vector_type(8)));
typedef float f32x4 __attribute__((ext_vector_type(4)));

__device__ inline unsigned short f2bf(float f) {    // RNE, finite inputs
    unsigned u = __float_as_uint(f);
    unsigned r = u + 0x7fffu + ((u >> 16) & 1u);
    return (unsigned short)(r >> 16);
}
__device__ inline float bflo(unsigned u) { return __uint_as_float(u << 16); }
__device__ inline float bfhi(unsigned u) { return __uint_as_float(u & 0xffff0000u); }

// ---------------- degree / CSR build ----------------
__global__ __launch_bounds__(256) void k_deg(const int* __restrict__ dst,
                                             int* __restrict__ deg) {
    int e = blockIdx.x * 256 + threadIdx.x;
    if (e < N_EDGES) atomicAdd(&deg[dst[e]], 1);
}

__global__ __launch_bounds__(256) void k_invdeg(const int* __restrict__ deg,
                                                float* __restrict__ invdeg) {
    int i = blockIdx.x * 256 + threadIdx.x;
    if (i < N_NODES) invdeg[i] = 1.0f / fmaxf((float)deg[i], 1.0f);
}

__global__ __launch_bounds__(256) void k_scan1(const int* __restrict__ deg,
                                               int* __restrict__ rowptr,
                                               int* __restrict__ bsum) {
    __shared__ int tmp[256];
    int t = threadIdx.x;
    int i = blockIdx.x * 256 + t;
    int v = (i < N_NODES) ? deg[i] : 0;
    tmp[t] = v;
    __syncthreads();
    #pragma unroll
    for (int off = 1; off < 256; off <<= 1) {
        int y = 0;
        if (t >= off) y = tmp[t - off];
        __syncthreads();
        if (t >= off) tmp[t] += y;
        __syncthreads();
    }
    if (i < N_NODES) rowptr[i] = tmp[t] - v;
    if (t == 255) bsum[blockIdx.x] = tmp[t];
}

__global__ __launch_bounds__(512) void k_scan2(int* __restrict__ bsum) {
    __shared__ int tmp[512];
    int t = threadIdx.x;
    int v = (t < NB) ? bsum[t] : 0;
    tmp[t] = v;
    __syncthreads();
    #pragma unroll
    for (int off = 1; off < 512; off <<= 1) {
        int y = 0;
        if (t >= off) y = tmp[t - off];
        __syncthreads();
        if (t >= off) tmp[t] += y;
        __syncthreads();
    }
    if (t < NB) bsum[t] = tmp[t] - v;
}

__global__ __launch_bounds__(256) void k_scan3(int* __restrict__ rowptr,
                                               int* __restrict__ cursor,
                                               const int* __restrict__ bsum) {
    int i = blockIdx.x * 256 + threadIdx.x;
    if (i < N_NODES) {
        int r = rowptr[i] + bsum[blockIdx.x];
        rowptr[i] = r;
        cursor[i] = r;
    }
}

__global__ __launch_bounds__(256) void k_fill(const int* __restrict__ src,
                                              const int* __restrict__ dst,
                                              int* __restrict__ cursor,
                                              int* __restrict__ eidx) {
    int e = blockIdx.x * 256 + threadIdx.x;
    if (e < N_EDGES) {
        int p = atomicAdd(&cursor[dst[e]], 1);
        eidx[p] = src[e];
    }
}

// ---------------- fp32 -> bf16 cast (x) ----------------
__global__ __launch_bounds__(256) void k_cast(const float* __restrict__ x,
                                              unsigned short* __restrict__ xb) {
    int idx = blockIdx.x * 256 + threadIdx.x;   // < N*32
    float4 v = ((const float4*)x)[idx];
    ushort4 o;
    o.x = f2bf(v.x); o.y = f2bf(v.y); o.z = f2bf(v.z); o.w = f2bf(v.w);
    ((ushort4*)xb)[idx] = o;
}

// ---------------- weight prep: WT[n][kcat] bf16, kcat = [Wr k | Wn k] -------
__global__ __launch_bounds__(256) void k_prepw(const float* __restrict__ Wr,
                                               const float* __restrict__ Wn,
                                               unsigned short* __restrict__ WT,
                                               int Nw) {
    int idx = blockIdx.x * 256 + threadIdx.x;   // < Nw*256
    int n = idx >> 8;
    int kc = idx & 255;
    float v = (kc < 128) ? Wr[kc * Nw + n] : Wn[(kc - 128) * Nw + n];
    WT[idx] = f2bf(v);
}

// ---------------- gather mean-aggregation (bf16), one wave per node --------
__global__ __launch_bounds__(256) void k_gather(const unsigned* __restrict__ hw,
                                                const int* __restrict__ eidx,
                                                const int* __restrict__ rowptr,
                                                const int* __restrict__ deg,
                                                const float* __restrict__ invdeg,
                                                unsigned* __restrict__ aggw) {
    int node = blockIdx.x * 4 + (threadIdx.x >> 6);
    int lane = threadIdx.x & 63;
    int start = rowptr[node];
    int cnt = deg[node];
    float ax = 0.0f, ay = 0.0f;
    int j = 0;
    for (; j + 4 <= cnt; j += 4) {
        int s0 = eidx[start + j];
        int s1 = eidx[start + j + 1];
        int s2 = eidx[start + j + 2];
        int s3 = eidx[start + j + 3];
        unsigned u0 = hw[s0 * 64 + lane];
        unsigned u1 = hw[s1 * 64 + lane];
        unsigned u2 = hw[s2 * 64 + lane];
        unsigned u3 = hw[s3 * 64 + lane];
        ax += bflo(u0) + bflo(u1) + bflo(u2) + bflo(u3);
        ay += bfhi(u0) + bfhi(u1) + bfhi(u2) + bfhi(u3);
    }
    for (; j < cnt; ++j) {
        unsigned u = hw[eidx[start + j] * 64 + lane];
        ax += bflo(u);
        ay += bfhi(u);
    }
    float id = invdeg[node];
    unsigned lo = f2bf(ax * id);
    unsigned hi = f2bf(ay * id);
    aggw[node * 64 + lane] = lo | (hi << 16);
}

// ---------------- MFMA dual-GEMM + bias + LayerNorm + ReLU (K=256 -> 128) --
// Block: 256 thr = 4 waves. Wave w: rows rt*16..+16 (rt=w>>1), cols ch*64..+64
// (ch=w&1). A = [h|agg] bf16 in LDS; B = WT[n][k] bf16 staged per 64-k chunk.
__global__ __launch_bounds__(256) void k_gemm_ln(
        const unsigned short* __restrict__ hb, const unsigned short* __restrict__ ab,
        const unsigned short* __restrict__ WT,
        const float* __restrict__ b, const float* __restrict__ g,
        const float* __restrict__ be, unsigned short* __restrict__ outb) {
    __shared__ unsigned short hl[32][136];
    __shared__ unsigned short al[32][136];
    __shared__ unsigned short bt[128][72];
    __shared__ float p1[2][32], p2[2][32];

    const int tid = threadIdx.x;
    const int lane = tid & 63;
    const int w = tid >> 6;
    const int quad = lane >> 4;
    const int l15 = lane & 15;
    const int rt = w >> 1;
    const int ch = w & 1;
    const int row0 = blockIdx.x * 32;

    // stage A (h and agg rows): 32 rows x 16 float4-chunks each
    #pragma unroll
    for (int t = 0; t < 2; ++t) {
        int idx = tid + t * 256;
        int r = idx >> 4;
        int c8 = idx & 15;
        *(float4*)&hl[r][c8 * 8] = ((const float4*)hb)[(size_t)(row0 + r) * 16 + c8];
        *(float4*)&al[r][c8 * 8] = ((const float4*)ab)[(size_t)(row0 + r) * 16 + c8];
    }

    f32x4 acc[4];
    #pragma unroll
    for (int t = 0; t < 4; ++t)
        #pragma unroll
        for (int r = 0; r < 4; ++r) acc[t][r] = 0.0f;

    #pragma unroll
    for (int kt = 0; kt < 4; ++kt) {
        __syncthreads();
        // stage B chunk: 128 n x 64 k bf16
        #pragma unroll
        for (int t = 0; t < 4; ++t) {
            int idx = tid + t * 256;
            int n = idx >> 3;
            int c8 = idx & 7;
            *(float4*)&bt[n][c8 * 8] = ((const float4*)WT)[n * 32 + kt * 8 + c8];
        }
        __syncthreads();
        #pragma unroll
        for (int ks = 0; ks < 2; ++ks) {
            const int ck = kt * 64 + ks * 32;
            const unsigned short* ap = (ck < 128)
                ? &hl[rt * 16 + l15][ck + quad * 8]
                : &al[rt * 16 + l15][ck - 128 + quad * 8];
            bf16x8 a = *(const bf16x8*)ap;
            #pragma unroll
            for (int t = 0; t < 4; ++t) {
                bf16x8 bb = *(const bf16x8*)&bt[ch * 64 + t * 16 + l15][ks * 32 + quad * 8];
                acc[t] = __builtin_amdgcn_mfma_f32_16x16x32_bf16(a, bb, acc[t], 0, 0, 0);
            }
        }
    }

    // epilogue: bias + LayerNorm(128) + ReLU -> bf16
    float bcol[4], gc[4], bec[4];
    #pragma unroll
    for (int t = 0; t < 4; ++t) {
        int col = ch * 64 + t * 16 + l15;
        bcol[t] = b[col]; gc[t] = g[col]; bec[t] = be[col];
    }
    float v[4][4];
    float s1[4], s2[4];
    #pragma unroll
    for (int r = 0; r < 4; ++r) { s1[r] = 0.0f; s2[r] = 0.0f; }
    #pragma unroll
    for (int t = 0; t < 4; ++t)
        #pragma unroll
        for (int r = 0; r < 4; ++r) {
            float x = acc[t][r] + bcol[t];
            v[t][r] = x;
            s1[r] += x;
            s2[r] += x * x;
        }
    #pragma unroll
    for (int m = 1; m <= 8; m <<= 1)
        #pragma unroll
        for (int r = 0; r < 4; ++r) {
            s1[r] += __shfl_xor(s1[r], m);
            s2[r] += __shfl_xor(s2[r], m);
        }
    if (l15 == 0) {
        #pragma unroll
        for (int r = 0; r < 4; ++r) {
            int rl = rt * 16 + quad * 4 + r;
            p1[ch][rl] = s1[r];
            p2[ch][rl] = s2[r];
        }
    }
    __syncthreads();
    #pragma unroll
    for (int r = 0; r < 4; ++r) {
        int rl = rt * 16 + quad * 4 + r;
        float S1 = p1[0][rl] + p1[1][rl];
        float S2 = p2[0][rl] + p2[1][rl];
        float mean = S1 * (1.0f / 128.0f);
        float var = S2 * (1.0f / 128.0f) - mean * mean;
        float rstd = rsqrtf(var + EPS);
        #pragma unroll
        for (int t = 0; t < 4; ++t) {
            float o = fmaxf((v[t][r] - mean) * rstd * gc[t] + bec[t], 0.0f);
            outb[(size_t)(row0 + rl) * 128 + ch * 64 + t * 16 + l15] = f2bf(o);
        }
    }
}

// ---------------- MFMA layer 2: K=256 -> 64 + bias + log_softmax -----------
// Wave w: rows rt*16..+16 (rt=w>>1), cols ch*32..+32 (ch=w&1), t-tiles 0..1.
__global__ __launch_bounds__(256) void k_l2(
        const unsigned short* __restrict__ hb, const unsigned short* __restrict__ ab,
        const unsigned short* __restrict__ WT,
        const float* __restrict__ b, float* __restrict__ out) {
    __shared__ unsigned short hl[32][136];
    __shared__ unsigned short al[32][136];
    __shared__ unsigned short bt[64][72];
    __shared__ float pmax[2][32], psum[2][32];

    const int tid = threadIdx.x;
    const int lane = tid & 63;
    const int w = tid >> 6;
    const int quad = lane >> 4;
    const int l15 = lane & 15;
    const int rt = w >> 1;
    const int ch = w & 1;
    const int row0 = blockIdx.x * 32;

    #pragma unroll
    for (int t = 0; t < 2; ++t) {
        int idx = tid + t * 256;
        int r = idx >> 4;
        int c8 = idx & 15;
        *(float4*)&hl[r][c8 * 8] = ((const float4*)hb)[(size_t)(row0 + r) * 16 + c8];
        *(float4*)&al[r][c8 * 8] = ((const float4*)ab)[(size_t)(row0 + r) * 16 + c8];
    }

    f32x4 acc[2];
    #pragma unroll
    for (int t = 0; t < 2; ++t)
        #pragma unroll
        for (int r = 0; r < 4; ++r) acc[t][r] = 0.0f;

    #pragma unroll
    for (int kt = 0; kt < 4; ++kt) {
        __syncthreads();
        #pragma unroll
        for (int t = 0; t < 2; ++t) {
            int idx = tid + t * 256;
            int n = idx >> 3;
            int c8 = idx & 7;
            *(float4*)&bt[n][c8 * 8] = ((const float4*)WT)[n * 32 + kt * 8 + c8];
        }
        __syncthreads();
        #pragma unroll
        for (int ks = 0; ks < 2; ++ks) {
            const int ck = kt * 64 + ks * 32;
            const unsigned short* ap = (ck < 128)
                ? &hl[rt * 16 + l15][ck + quad * 8]
                : &al[rt * 16 + l15][ck - 128 + quad * 8];
            bf16x8 a = *(const bf16x8*)ap;
            #pragma unroll
            for (int t = 0; t < 2; ++t) {
                bf16x8 bb = *(const bf16x8*)&bt[ch * 32 + t * 16 + l15][ks * 32 + quad * 8];
                acc[t] = __builtin_amdgcn_mfma_f32_16x16x32_bf16(a, bb, acc[t], 0, 0, 0);
            }
        }
    }

    // epilogue: bias + log_softmax(64)
    float v[2][4];
    #pragma unroll
    for (int t = 0; t < 2; ++t) {
        float bc = b[ch * 32 + t * 16 + l15];
        #pragma unroll
        for (int r = 0; r < 4; ++r) v[t][r] = acc[t][r] + bc;
    }
    float mx[4];
    #pragma unroll
    for (int r = 0; r < 4; ++r) mx[r] = fmaxf(v[0][r], v[1][r]);
    #pragma unroll
    for (int m = 1; m <= 8; m <<= 1)
        #pragma unroll
        for (int r = 0; r < 4; ++r) mx[r] = fmaxf(mx[r], __shfl_xor(mx[r], m));
    if (l15 == 0) {
        #pragma unroll
        for (int r = 0; r < 4; ++r) pmax[ch][rt * 16 + quad * 4 + r] = mx[r];
    }
    __syncthreads();
    float M[4], s[4];
    #pragma unroll
    for (int r = 0; r < 4; ++r) {
        int rl = rt * 16 + quad * 4 + r;
        M[r] = fmaxf(pmax[0][rl], pmax[1][rl]);
        s[r] = __expf(v[0][r] - M[r]) + __expf(v[1][r] - M[r]);
    }
    #pragma unroll
    for (int m = 1; m <= 8; m <<= 1)
        #pragma unroll
        for (int r = 0; r < 4; ++r) s[r] += __shfl_xor(s[r], m);
    if (l15 == 0) {
        #pragma unroll
        for (int r = 0; r < 4; ++r) psum[ch][rt * 16 + quad * 4 + r] = s[r];
    }
    __syncthreads();
    #pragma unroll
    for (int r = 0; r < 4; ++r) {
        int rl = rt * 16 + quad * 4 + r;
        float L = logf(psum[0][rl] + psum[1][rl]);
        #pragma unroll
        for (int t = 0; t < 2; ++t)
            out[(size_t)(row0 + rl) * 64 + ch * 32 + t * 16 + l15] = v[t][r] - M[r] - L;
    }
}

extern "C" void kernel_launch(void* const* d_in, const int* in_sizes, int n_in,
                              void* d_out, int out_size, void* d_ws, size_t ws_size,
                              hipStream_t stream) {
    const float* x   = (const float*)d_in[0];
    const int* esrc  = (const int*)d_in[1];
    const int* edst  = (const int*)d_in[2];
    const float* Wr0 = (const float*)d_in[3];
    const float* Wn0 = (const float*)d_in[4];
    const float* b0  = (const float*)d_in[5];
    const float* g0  = (const float*)d_in[6];
    const float* be0 = (const float*)d_in[7];
    const float* Wr1 = (const float*)d_in[8];
    const float* Wn1 = (const float*)d_in[9];
    const float* b1  = (const float*)d_in[10];
    const float* g1  = (const float*)d_in[11];
    const float* be1 = (const float*)d_in[12];
    const float* Wr2 = (const float*)d_in[13];
    const float* Wn2 = (const float*)d_in[14];
    const float* b2  = (const float*)d_in[15];
    float* out = (float*)d_out;

    char* p = (char*)d_ws;
    auto alloc = [&](size_t bytes) {
        void* r = (void*)p;
        p += (bytes + 255) & ~(size_t)255;
        return r;
    };
    int*   deg    = (int*)  alloc(N_NODES * 4);
    float* invdeg = (float*)alloc(N_NODES * 4);
    int*   rowptr = (int*)  alloc(N_NODES * 4);
    int*   cursor = (int*)  alloc(N_NODES * 4);
    int*   bsum   = (int*)  alloc(NB * 4);
    int*   eidx   = (int*)  alloc((size_t)N_EDGES * 4);
    unsigned short* xb   = (unsigned short*)alloc((size_t)N_NODES * 128 * 2); // also h2
    unsigned short* h1   = (unsigned short*)alloc((size_t)N_NODES * 128 * 2);
    unsigned short* aggb = (unsigned short*)alloc((size_t)N_NODES * 128 * 2);
    unsigned short* WT0  = (unsigned short*)alloc(128 * 256 * 2);
    unsigned short* WT1  = (unsigned short*)alloc(128 * 256 * 2);
    unsigned short* WT2  = (unsigned short*)alloc(64 * 256 * 2);

    // prep: cast x to bf16, transpose+cast weights
    k_cast<<<N_NODES * 32 / 256, 256, 0, stream>>>(x, xb);
    k_prepw<<<128, 256, 0, stream>>>(Wr0, Wn0, WT0, 128);
    k_prepw<<<128, 256, 0, stream>>>(Wr1, Wn1, WT1, 128);
    k_prepw<<<64, 256, 0, stream>>>(Wr2, Wn2, WT2, 64);

    // CSR build
    hipMemsetAsync(deg, 0, N_NODES * sizeof(int), stream);
    k_deg<<<(N_EDGES + 255) / 256, 256, 0, stream>>>(edst, deg);
    k_invdeg<<<NB, 256, 0, stream>>>(deg, invdeg);
    k_scan1<<<NB, 256, 0, stream>>>(deg, rowptr, bsum);
    k_scan2<<<1, 512, 0, stream>>>(bsum);
    k_scan3<<<NB, 256, 0, stream>>>(rowptr, cursor, bsum);
    k_fill<<<(N_EDGES + 255) / 256, 256, 0, stream>>>(esrc, edst, cursor, eidx);

    // layer 0
    k_gather<<<N_NODES / 4, 256, 0, stream>>>((const unsigned*)xb, eidx, rowptr, deg, invdeg, (unsigned*)aggb);
    k_gemm_ln<<<N_NODES / 32, 256, 0, stream>>>(xb, aggb, WT0, b0, g0, be0, h1);

    // layer 1 (h2 reuses xb's buffer)
    k_gather<<<N_NODES / 4, 256, 0, stream>>>((const unsigned*)h1, eidx, rowptr, deg, invdeg, (unsigned*)aggb);
    k_gemm_ln<<<N_NODES / 32, 256, 0, stream>>>(h1, aggb, WT1, b1, g1, be1, xb);

    // layer 2 + log_softmax
    k_gather<<<N_NODES / 4, 256, 0, stream>>>((const unsigned*)xb, eidx, rowptr, deg, invdeg, (unsigned*)aggb);
    k_l2<<<N_NODES / 32, 256, 0, stream>>>(xb, aggb, WT2, b2, out);
}

// Round 4
// 529.449 us; speedup vs baseline: 16.5424x; 1.1432x over previous
//
#include <hip/hip_runtime.h>
#include <math.h>

#define N_NODES 100000
#define N_EDGES 1600000
#define EPS 1e-5f
#define NB 391              // ceil(100000/256) scan blocks

typedef __bf16 bf16x8 __attribute__((ext_vector_type(8)));
typedef float f32x4 __attribute__((ext_vector_type(4)));

__device__ inline unsigned short f2bf(float f) {    // RNE, finite inputs
    unsigned u = __float_as_uint(f);
    unsigned r = u + 0x7fffu + ((u >> 16) & 1u);
    return (unsigned short)(r >> 16);
}
__device__ inline float bflo(unsigned u) { return __uint_as_float(u << 16); }
__device__ inline float bfhi(unsigned u) { return __uint_as_float(u & 0xffff0000u); }
__device__ inline unsigned pack2(float lo, float hi) {
    return (unsigned)f2bf(lo) | ((unsigned)f2bf(hi) << 16);
}

// ---------------- degree / CSR build ----------------
__global__ __launch_bounds__(256) void k_deg(const int* __restrict__ dst,
                                             int* __restrict__ deg) {
    int e = blockIdx.x * 256 + threadIdx.x;
    if (e < N_EDGES) atomicAdd(&deg[dst[e]], 1);
}

__global__ __launch_bounds__(256) void k_invdeg(const int* __restrict__ deg,
                                                float* __restrict__ invdeg) {
    int i = blockIdx.x * 256 + threadIdx.x;
    if (i < N_NODES) invdeg[i] = 1.0f / fmaxf((float)deg[i], 1.0f);
}

__global__ __launch_bounds__(256) void k_scan1(const int* __restrict__ deg,
                                               int* __restrict__ rowptr,
                                               int* __restrict__ bsum) {
    __shared__ int tmp[256];
    int t = threadIdx.x;
    int i = blockIdx.x * 256 + t;
    int v = (i < N_NODES) ? deg[i] : 0;
    tmp[t] = v;
    __syncthreads();
    #pragma unroll
    for (int off = 1; off < 256; off <<= 1) {
        int y = 0;
        if (t >= off) y = tmp[t - off];
        __syncthreads();
        if (t >= off) tmp[t] += y;
        __syncthreads();
    }
    if (i < N_NODES) rowptr[i] = tmp[t] - v;
    if (t == 255) bsum[blockIdx.x] = tmp[t];
}

__global__ __launch_bounds__(512) void k_scan2(int* __restrict__ bsum) {
    __shared__ int tmp[512];
    int t = threadIdx.x;
    int v = (t < NB) ? bsum[t] : 0;
    tmp[t] = v;
    __syncthreads();
    #pragma unroll
    for (int off = 1; off < 512; off <<= 1) {
        int y = 0;
        if (t >= off) y = tmp[t - off];
        __syncthreads();
        if (t >= off) tmp[t] += y;
        __syncthreads();
    }
    if (t < NB) bsum[t] = tmp[t] - v;
}

__global__ __launch_bounds__(256) void k_scan3(int* __restrict__ rowptr,
                                               int* __restrict__ cursor,
                                               const int* __restrict__ bsum) {
    int i = blockIdx.x * 256 + threadIdx.x;
    if (i < N_NODES) {
        int r = rowptr[i] + bsum[blockIdx.x];
        rowptr[i] = r;
        cursor[i] = r;
    }
}

// XCD-ranged CSR fill: block handles edge chunk (blockIdx>>3) for dst range
// (blockIdx&7). Round-robin block->XCD dispatch makes each eidx region
// single-XCD-writer -> full-line L2 writeback instead of 64B/store.
__global__ __launch_bounds__(256) void k_fillr(const int* __restrict__ src,
                                               const int* __restrict__ dst,
                                               int* __restrict__ cursor,
                                               int* __restrict__ eidx) {
    const int r = blockIdx.x & 7;
    const int c = blockIdx.x >> 3;          // 128 chunks of 12500 edges
    const int lo = r * 12500;
    const int base = c * 12500;
    for (int i = base + threadIdx.x; i < base + 12500; i += 256) {
        int d = dst[i];
        if ((unsigned)(d - lo) < 12500u) {
            int p = atomicAdd(&cursor[d], 1);
            eidx[p] = src[i];
        }
    }
}

// ---------------- fp32 -> bf16 cast (x) ----------------
__global__ __launch_bounds__(256) void k_cast(const float* __restrict__ x,
                                              unsigned short* __restrict__ xb) {
    int idx = blockIdx.x * 256 + threadIdx.x;   // < N*32
    float4 v = ((const float4*)x)[idx];
    ushort4 o;
    o.x = f2bf(v.x); o.y = f2bf(v.y); o.z = f2bf(v.z); o.w = f2bf(v.w);
    ((ushort4*)xb)[idx] = o;
}

// ---------------- weight prep: WT[n][kcat] bf16, kcat = [Wr k | Wn k] -------
__global__ __launch_bounds__(256) void k_prepw(const float* __restrict__ Wr,
                                               const float* __restrict__ Wn,
                                               unsigned short* __restrict__ WT,
                                               int Nw) {
    int idx = blockIdx.x * 256 + threadIdx.x;   // < Nw*256
    int n = idx >> 8;
    int kc = idx & 255;
    float v = (kc < 128) ? Wr[kc * Nw + n] : Wn[(kc - 128) * Nw + n];
    WT[idx] = f2bf(v);
}

// weight prep layer2: WT2cat[n][k], n<64 -> Wr2 col n, n>=64 -> Wn2 col n-64
__global__ __launch_bounds__(256) void k_prepw2(const float* __restrict__ Wr,
                                                const float* __restrict__ Wn,
                                                unsigned short* __restrict__ WT) {
    int idx = blockIdx.x * 256 + threadIdx.x;   // < 128*128
    int n = idx >> 7;
    int k = idx & 127;
    float v = (n < 64) ? Wr[k * 64 + n] : Wn[k * 64 + (n - 64)];
    WT[n * 128 + k] = f2bf(v);
}

// ---------------- gather mean-aggregation (bf16, 128-dim) ------------------
// Wave = 2 half-waves x 32 lanes; each half processes different edges,
// 8B/lane loads, 8 rows in flight; cross-half shuffle-reduce at the end.
__global__ __launch_bounds__(256) void k_gather(const uint2* __restrict__ hw2,
                                                const int* __restrict__ eidx,
                                                const int* __restrict__ rowptr,
                                                const int* __restrict__ deg,
                                                const float* __restrict__ invdeg,
                                                uint2* __restrict__ aggw2) {
    int node = blockIdx.x * 4 + (threadIdx.x >> 6);
    int lane = threadIdx.x & 63;
    int half = lane >> 5;
    int l = lane & 31;
    int start = rowptr[node];
    int cnt = deg[node];
    float a0 = 0.0f, a1 = 0.0f, a2 = 0.0f, a3 = 0.0f;
    int j = 0;
    for (; j + 8 <= cnt; j += 8) {
        int e = start + j + half * 4;
        int s0 = eidx[e], s1 = eidx[e + 1], s2 = eidx[e + 2], s3 = eidx[e + 3];
        uint2 u0 = hw2[s0 * 32 + l];
        uint2 u1 = hw2[s1 * 32 + l];
        uint2 u2 = hw2[s2 * 32 + l];
        uint2 u3 = hw2[s3 * 32 + l];
        a0 += bflo(u0.x) + bflo(u1.x) + bflo(u2.x) + bflo(u3.x);
        a1 += bfhi(u0.x) + bfhi(u1.x) + bfhi(u2.x) + bfhi(u3.x);
        a2 += bflo(u0.y) + bflo(u1.y) + bflo(u2.y) + bflo(u3.y);
        a3 += bfhi(u0.y) + bfhi(u1.y) + bfhi(u2.y) + bfhi(u3.y);
    }
    for (; j + 2 <= cnt; j += 2) {
        int s0 = eidx[start + j + half];
        uint2 u = hw2[s0 * 32 + l];
        a0 += bflo(u.x); a1 += bfhi(u.x);
        a2 += bflo(u.y); a3 += bfhi(u.y);
    }
    if (j < cnt && half == 0) {
        uint2 u = hw2[eidx[start + j] * 32 + l];
        a0 += bflo(u.x); a1 += bfhi(u.x);
        a2 += bflo(u.y); a3 += bfhi(u.y);
    }
    a0 += __shfl_xor(a0, 32);
    a1 += __shfl_xor(a1, 32);
    a2 += __shfl_xor(a2, 32);
    a3 += __shfl_xor(a3, 32);
    if (half == 0) {
        float id = invdeg[node];
        uint2 o;
        o.x = pack2(a0 * id, a1 * id);
        o.y = pack2(a2 * id, a3 * id);
        aggw2[node * 32 + l] = o;
    }
}

// ---------------- MFMA dual-GEMM + bias + LayerNorm + ReLU (K=256 -> 128) --
__global__ __launch_bounds__(256) void k_gemm_ln(
        const unsigned short* __restrict__ hb, const unsigned short* __restrict__ ab,
        const unsigned short* __restrict__ WT,
        const float* __restrict__ b, const float* __restrict__ g,
        const float* __restrict__ be, unsigned short* __restrict__ outb) {
    __shared__ unsigned short hl[32][136];
    __shared__ unsigned short al[32][136];
    __shared__ unsigned short bt[128][72];
    __shared__ float p1[2][32], p2[2][32];

    const int tid = threadIdx.x;
    const int lane = tid & 63;
    const int w = tid >> 6;
    const int quad = lane >> 4;
    const int l15 = lane & 15;
    const int rt = w >> 1;
    const int ch = w & 1;
    const int row0 = blockIdx.x * 32;

    #pragma unroll
    for (int t = 0; t < 2; ++t) {
        int idx = tid + t * 256;
        int r = idx >> 4;
        int c8 = idx & 15;
        *(float4*)&hl[r][c8 * 8] = ((const float4*)hb)[(size_t)(row0 + r) * 16 + c8];
        *(float4*)&al[r][c8 * 8] = ((const float4*)ab)[(size_t)(row0 + r) * 16 + c8];
    }

    f32x4 acc[4];
    #pragma unroll
    for (int t = 0; t < 4; ++t)
        #pragma unroll
        for (int r = 0; r < 4; ++r) acc[t][r] = 0.0f;

    #pragma unroll
    for (int kt = 0; kt < 4; ++kt) {
        __syncthreads();
        #pragma unroll
        for (int t = 0; t < 4; ++t) {
            int idx = tid + t * 256;
            int n = idx >> 3;
            int c8 = idx & 7;
            *(float4*)&bt[n][c8 * 8] = ((const float4*)WT)[n * 32 + kt * 8 + c8];
        }
        __syncthreads();
        #pragma unroll
        for (int ks = 0; ks < 2; ++ks) {
            const int ck = kt * 64 + ks * 32;
            const unsigned short* ap = (ck < 128)
                ? &hl[rt * 16 + l15][ck + quad * 8]
                : &al[rt * 16 + l15][ck - 128 + quad * 8];
            bf16x8 a = *(const bf16x8*)ap;
            #pragma unroll
            for (int t = 0; t < 4; ++t) {
                bf16x8 bb = *(const bf16x8*)&bt[ch * 64 + t * 16 + l15][ks * 32 + quad * 8];
                acc[t] = __builtin_amdgcn_mfma_f32_16x16x32_bf16(a, bb, acc[t], 0, 0, 0);
            }
        }
    }

    float bcol[4], gc[4], bec[4];
    #pragma unroll
    for (int t = 0; t < 4; ++t) {
        int col = ch * 64 + t * 16 + l15;
        bcol[t] = b[col]; gc[t] = g[col]; bec[t] = be[col];
    }
    float v[4][4];
    float s1[4], s2[4];
    #pragma unroll
    for (int r = 0; r < 4; ++r) { s1[r] = 0.0f; s2[r] = 0.0f; }
    #pragma unroll
    for (int t = 0; t < 4; ++t)
        #pragma unroll
        for (int r = 0; r < 4; ++r) {
            float x = acc[t][r] + bcol[t];
            v[t][r] = x;
            s1[r] += x;
            s2[r] += x * x;
        }
    #pragma unroll
    for (int m = 1; m <= 8; m <<= 1)
        #pragma unroll
        for (int r = 0; r < 4; ++r) {
            s1[r] += __shfl_xor(s1[r], m);
            s2[r] += __shfl_xor(s2[r], m);
        }
    if (l15 == 0) {
        #pragma unroll
        for (int r = 0; r < 4; ++r) {
            int rl = rt * 16 + quad * 4 + r;
            p1[ch][rl] = s1[r];
            p2[ch][rl] = s2[r];
        }
    }
    __syncthreads();
    #pragma unroll
    for (int r = 0; r < 4; ++r) {
        int rl = rt * 16 + quad * 4 + r;
        float S1 = p1[0][rl] + p1[1][rl];
        float S2 = p2[0][rl] + p2[1][rl];
        float mean = S1 * (1.0f / 128.0f);
        float var = S2 * (1.0f / 128.0f) - mean * mean;
        float rstd = rsqrtf(var + EPS);
        #pragma unroll
        for (int t = 0; t < 4; ++t) {
            float o = fmaxf((v[t][r] - mean) * rstd * gc[t] + bec[t], 0.0f);
            outb[(size_t)(row0 + rl) * 128 + ch * 64 + t * 16 + l15] = f2bf(o);
        }
    }
}

// ---------------- layer 2 GEMM: zy = h2 @ [Wr2|Wn2] (+b2 on z half) --------
__global__ __launch_bounds__(256) void k_gemm2(
        const unsigned short* __restrict__ hb, const unsigned short* __restrict__ WT,
        const float* __restrict__ b2, unsigned short* __restrict__ zyb) {
    __shared__ unsigned short hl[32][136];
    __shared__ unsigned short bt[128][136];

    const int tid = threadIdx.x;
    const int lane = tid & 63;
    const int w = tid >> 6;
    const int quad = lane >> 4;
    const int l15 = lane & 15;
    const int rt = w >> 1;
    const int ch = w & 1;
    const int row0 = blockIdx.x * 32;

    #pragma unroll
    for (int t = 0; t < 2; ++t) {
        int idx = tid + t * 256;
        int r = idx >> 4;
        int c8 = idx & 15;
        *(float4*)&hl[r][c8 * 8] = ((const float4*)hb)[(size_t)(row0 + r) * 16 + c8];
    }
    #pragma unroll
    for (int t = 0; t < 8; ++t) {
        int idx = tid + t * 256;
        int n = idx >> 4;
        int c8 = idx & 15;
        *(float4*)&bt[n][c8 * 8] = ((const float4*)WT)[n * 16 + c8];
    }
    __syncthreads();

    f32x4 acc[4];
    #pragma unroll
    for (int t = 0; t < 4; ++t)
        #pragma unroll
        for (int r = 0; r < 4; ++r) acc[t][r] = 0.0f;

    #pragma unroll
    for (int ks = 0; ks < 4; ++ks) {
        bf16x8 a = *(const bf16x8*)&hl[rt * 16 + l15][ks * 32 + quad * 8];
        #pragma unroll
        for (int t = 0; t < 4; ++t) {
            bf16x8 bb = *(const bf16x8*)&bt[ch * 64 + t * 16 + l15][ks * 32 + quad * 8];
            acc[t] = __builtin_amdgcn_mfma_f32_16x16x32_bf16(a, bb, acc[t], 0, 0, 0);
        }
    }

    #pragma unroll
    for (int t = 0; t < 4; ++t) {
        int col = ch * 64 + t * 16 + l15;
        float bc = (col < 64) ? b2[col] : 0.0f;
        #pragma unroll
        for (int r = 0; r < 4; ++r) {
            int rl = rt * 16 + quad * 4 + r;
            zyb[(size_t)(row0 + rl) * 128 + col] = f2bf(acc[t][r] + bc);
        }
    }
}

// ------- final: gather-mean y (64-dim) + z + log_softmax, fp32 out ---------
// Half-wave (32 lanes) per node; lane l holds cols 2l, 2l+1.
__global__ __launch_bounds__(256) void k_l2g(const unsigned* __restrict__ zyw,
                                             const int* __restrict__ eidx,
                                             const int* __restrict__ rowptr,
                                             const int* __restrict__ deg,
                                             const float* __restrict__ invdeg,
                                             float* __restrict__ out) {
    int node = blockIdx.x * 8 + (threadIdx.x >> 5);
    int l = threadIdx.x & 31;
    int start = rowptr[node];
    int cnt = deg[node];
    float ax = 0.0f, ay = 0.0f;
    int j = 0;
    for (; j + 4 <= cnt; j += 4) {
        int s0 = eidx[start + j];
        int s1 = eidx[start + j + 1];
        int s2 = eidx[start + j + 2];
        int s3 = eidx[start + j + 3];
        unsigned u0 = zyw[s0 * 64 + 32 + l];
        unsigned u1 = zyw[s1 * 64 + 32 + l];
        unsigned u2 = zyw[s2 * 64 + 32 + l];
        unsigned u3 = zyw[s3 * 64 + 32 + l];
        ax += bflo(u0) + bflo(u1) + bflo(u2) + bflo(u3);
        ay += bfhi(u0) + bfhi(u1) + bfhi(u2) + bfhi(u3);
    }
    for (; j < cnt; ++j) {
        unsigned u = zyw[eidx[start + j] * 64 + 32 + l];
        ax += bflo(u);
        ay += bfhi(u);
    }
    float id = invdeg[node];
    unsigned uz = zyw[node * 64 + l];
    float v0 = bflo(uz) + ax * id;
    float v1 = bfhi(uz) + ay * id;

    float m = fmaxf(v0, v1);
    #pragma unroll
    for (int msk = 1; msk <= 16; msk <<= 1) m = fmaxf(m, __shfl_xor(m, msk, 32));
    float s = __expf(v0 - m) + __expf(v1 - m);
    #pragma unroll
    for (int msk = 1; msk <= 16; msk <<= 1) s += __shfl_xor(s, msk, 32);
    float L = logf(s);
    float2 o;
    o.x = v0 - m - L;
    o.y = v1 - m - L;
    ((float2*)out)[(size_t)node * 32 + l] = o;
}

extern "C" void kernel_launch(void* const* d_in, const int* in_sizes, int n_in,
                              void* d_out, int out_size, void* d_ws, size_t ws_size,
                              hipStream_t stream) {
    const float* x   = (const float*)d_in[0];
    const int* esrc  = (const int*)d_in[1];
    const int* edst  = (const int*)d_in[2];
    const float* Wr0 = (const float*)d_in[3];
    const float* Wn0 = (const float*)d_in[4];
    const float* b0  = (const float*)d_in[5];
    const float* g0  = (const float*)d_in[6];
    const float* be0 = (const float*)d_in[7];
    const float* Wr1 = (const float*)d_in[8];
    const float* Wn1 = (const float*)d_in[9];
    const float* b1  = (const float*)d_in[10];
    const float* g1  = (const float*)d_in[11];
    const float* be1 = (const float*)d_in[12];
    const float* Wr2 = (const float*)d_in[13];
    const float* Wn2 = (const float*)d_in[14];
    const float* b2  = (const float*)d_in[15];
    float* out = (float*)d_out;

    char* p = (char*)d_ws;
    auto alloc = [&](size_t bytes) {
        void* r = (void*)p;
        p += (bytes + 255) & ~(size_t)255;
        return r;
    };
    int*   deg    = (int*)  alloc(N_NODES * 4);
    float* invdeg = (float*)alloc(N_NODES * 4);
    int*   rowptr = (int*)  alloc(N_NODES * 4);
    int*   cursor = (int*)  alloc(N_NODES * 4);
    int*   bsum   = (int*)  alloc(NB * 4);
    int*   eidx   = (int*)  alloc((size_t)N_EDGES * 4);
    unsigned short* xb   = (unsigned short*)alloc((size_t)N_NODES * 128 * 2); // also h2
    unsigned short* h1   = (unsigned short*)alloc((size_t)N_NODES * 128 * 2); // also zy
    unsigned short* aggb = (unsigned short*)alloc((size_t)N_NODES * 128 * 2);
    unsigned short* WT0  = (unsigned short*)alloc(128 * 256 * 2);
    unsigned short* WT1  = (unsigned short*)alloc(128 * 256 * 2);
    unsigned short* WT2  = (unsigned short*)alloc(128 * 128 * 2);

    // prep: cast x to bf16, transpose+cast weights
    k_cast<<<N_NODES * 32 / 256, 256, 0, stream>>>(x, xb);
    k_prepw<<<128, 256, 0, stream>>>(Wr0, Wn0, WT0, 128);
    k_prepw<<<128, 256, 0, stream>>>(Wr1, Wn1, WT1, 128);
    k_prepw2<<<64, 256, 0, stream>>>(Wr2, Wn2, WT2);

    // CSR build
    hipMemsetAsync(deg, 0, N_NODES * sizeof(int), stream);
    k_deg<<<(N_EDGES + 255) / 256, 256, 0, stream>>>(edst, deg);
    k_invdeg<<<NB, 256, 0, stream>>>(deg, invdeg);
    k_scan1<<<NB, 256, 0, stream>>>(deg, rowptr, bsum);
    k_scan2<<<1, 512, 0, stream>>>(bsum);
    k_scan3<<<NB, 256, 0, stream>>>(rowptr, cursor, bsum);
    k_fillr<<<1024, 256, 0, stream>>>(esrc, edst, cursor, eidx);

    // layer 0
    k_gather<<<N_NODES / 4, 256, 0, stream>>>((const uint2*)xb, eidx, rowptr, deg, invdeg, (uint2*)aggb);
    k_gemm_ln<<<N_NODES / 32, 256, 0, stream>>>(xb, aggb, WT0, b0, g0, be0, h1);

    // layer 1 (h2 goes back into xb's buffer)
    k_gather<<<N_NODES / 4, 256, 0, stream>>>((const uint2*)h1, eidx, rowptr, deg, invdeg, (uint2*)aggb);
    k_gemm_ln<<<N_NODES / 32, 256, 0, stream>>>(h1, aggb, WT1, b1, g1, be1, xb);

    // layer 2: zy = h2 @ [Wr2|Wn2] (+b2), then gather y-half + log_softmax
    k_gemm2<<<N_NODES / 32, 256, 0, stream>>>(xb, WT2, b2, h1);
    k_l2g<<<N_NODES / 8, 256, 0, stream>>>((const unsigned*)h1, eidx, rowptr, deg, invdeg, out);
}

// Round 5
// 464.414 us; speedup vs baseline: 18.8589x; 1.1400x over previous
//
#include <hip/hip_runtime.h>
#include <math.h>

#define N_NODES 100000
#define N_EDGES 1600000
#define EPS 1e-5f
#define NB 391              // ceil(100000/256) scan blocks
#define NC 256              // edge chunks
#define CHUNK 6250          // N_EDGES / NC
#define NR 98               // ceil(100000/1024) dst ranges
#define RSZ 1024            // nodes per range

typedef __bf16 bf16x8 __attribute__((ext_vector_type(8)));
typedef float f32x4 __attribute__((ext_vector_type(4)));

__device__ inline unsigned short f2bf(float f) {    // RNE, finite inputs
    unsigned u = __float_as_uint(f);
    unsigned r = u + 0x7fffu + ((u >> 16) & 1u);
    return (unsigned short)(r >> 16);
}
__device__ inline float bflo(unsigned u) { return __uint_as_float(u << 16); }
__device__ inline float bfhi(unsigned u) { return __uint_as_float(u & 0xffff0000u); }
__device__ inline unsigned pack2(float lo, float hi) {
    return (unsigned)f2bf(lo) | ((unsigned)f2bf(hi) << 16);
}

// ============ CSR build, no global atomics ============
// Pass 1: per-chunk histogram of dst-range (LDS atomics only)
__global__ __launch_bounds__(256) void k_count(const int* __restrict__ dst,
                                               int* __restrict__ cntG) {
    __shared__ int hist[NR];
    int t = threadIdx.x, c = blockIdx.x;
    for (int i = t; i < NR; i += 256) hist[i] = 0;
    __syncthreads();
    int base = c * CHUNK;
    for (int i = base + t; i < base + CHUNK; i += 256)
        atomicAdd(&hist[dst[i] >> 10], 1);
    __syncthreads();
    for (int i = t; i < NR; i += 256) cntG[i * NC + c] = hist[i];
}

// Pass 2: exclusive scan of cntG (NR*NC = 25088 entries, range-major), 1 block
__global__ __launch_bounds__(256) void k_scanA(int* __restrict__ cntG) {
    __shared__ int ts[256];
    int t = threadIdx.x;
    const int PER = (NR * NC) / 256;   // 98
    int s = 0;
    for (int i = 0; i < PER; ++i) s += cntG[t * PER + i];
    ts[t] = s;
    __syncthreads();
    #pragma unroll
    for (int off = 1; off < 256; off <<= 1) {
        int y = 0;
        if (t >= off) y = ts[t - off];
        __syncthreads();
        if (t >= off) ts[t] += y;
        __syncthreads();
    }
    int run = ts[t] - s;               // exclusive
    for (int i = 0; i < PER; ++i) {
        int v = cntG[t * PER + i];
        cntG[t * PER + i] = run;
        run += v;
    }
}

// Pass 3: bin edges by dst-range; per-(chunk,range) contiguous output streams
__global__ __launch_bounds__(256) void k_bin(const int* __restrict__ src,
                                             const int* __restrict__ dst,
                                             const int* __restrict__ baseG,
                                             int* __restrict__ bsrc,
                                             int* __restrict__ bdst) {
    __shared__ int cur[NR];
    int t = threadIdx.x, c = blockIdx.x;
    for (int i = t; i < NR; i += 256) cur[i] = baseG[i * NC + c];
    __syncthreads();
    int base = c * CHUNK;
    for (int i = base + t; i < base + CHUNK; i += 256) {
        int d = dst[i];
        int s = src[i];
        int p = atomicAdd(&cur[d >> 10], 1);
        bsrc[p] = s;
        bdst[p] = d;
    }
}

// Pass 4: per-range node histogram -> deg (coalesced write, no global atomics)
__global__ __launch_bounds__(256) void k_nodec(const int* __restrict__ bdst,
                                               const int* __restrict__ baseG,
                                               int* __restrict__ deg) {
    __shared__ int hist[RSZ];
    int r = blockIdx.x, t = threadIdx.x;
    for (int i = t; i < RSZ; i += 256) hist[i] = 0;
    __syncthreads();
    int s0 = baseG[r * NC];
    int s1 = (r == NR - 1) ? N_EDGES : baseG[(r + 1) * NC];
    int nbase = r << 10;
    for (int i = s0 + t; i < s1; i += 256)
        atomicAdd(&hist[bdst[i] - nbase], 1);
    __syncthreads();
    for (int i = t; i < RSZ && nbase + i < N_NODES; i += 256)
        deg[nbase + i] = hist[i];
}

// Pass 5: place srcs at rowptr positions; LDS cursor; single-block eidx region
__global__ __launch_bounds__(256) void k_place(const int* __restrict__ bsrc,
                                               const int* __restrict__ bdst,
                                               const int* __restrict__ baseG,
                                               const int* __restrict__ rowptr,
                                               int* __restrict__ eidx) {
    __shared__ int cur[RSZ];
    int r = blockIdx.x, t = threadIdx.x;
    int nbase = r << 10;
    for (int i = t; i < RSZ; i += 256)
        cur[i] = (nbase + i < N_NODES) ? rowptr[nbase + i] : 0;
    __syncthreads();
    int s0 = baseG[r * NC];
    int s1 = (r == NR - 1) ? N_EDGES : baseG[(r + 1) * NC];
    for (int i = s0 + t; i < s1; i += 256) {
        int d = bdst[i];
        int s = bsrc[i];
        int p = atomicAdd(&cur[d - nbase], 1);
        eidx[p] = s;
    }
}

// ============ node-level rowptr scan ============
__global__ __launch_bounds__(256) void k_invdeg(const int* __restrict__ deg,
                                                float* __restrict__ invdeg) {
    int i = blockIdx.x * 256 + threadIdx.x;
    if (i < N_NODES) invdeg[i] = 1.0f / fmaxf((float)deg[i], 1.0f);
}

__global__ __launch_bounds__(256) void k_scan1(const int* __restrict__ deg,
                                               int* __restrict__ rowptr,
                                               int* __restrict__ bsum) {
    __shared__ int tmp[256];
    int t = threadIdx.x;
    int i = blockIdx.x * 256 + t;
    int v = (i < N_NODES) ? deg[i] : 0;
    tmp[t] = v;
    __syncthreads();
    #pragma unroll
    for (int off = 1; off < 256; off <<= 1) {
        int y = 0;
        if (t >= off) y = tmp[t - off];
        __syncthreads();
        if (t >= off) tmp[t] += y;
        __syncthreads();
    }
    if (i < N_NODES) rowptr[i] = tmp[t] - v;
    if (t == 255) bsum[blockIdx.x] = tmp[t];
}

__global__ __launch_bounds__(512) void k_scan2(int* __restrict__ bsum) {
    __shared__ int tmp[512];
    int t = threadIdx.x;
    int v = (t < NB) ? bsum[t] : 0;
    tmp[t] = v;
    __syncthreads();
    #pragma unroll
    for (int off = 1; off < 512; off <<= 1) {
        int y = 0;
        if (t >= off) y = tmp[t - off];
        __syncthreads();
        if (t >= off) tmp[t] += y;
        __syncthreads();
    }
    if (t < NB) bsum[t] = tmp[t] - v;
}

__global__ __launch_bounds__(256) void k_scan3(int* __restrict__ rowptr,
                                               const int* __restrict__ bsum) {
    int i = blockIdx.x * 256 + threadIdx.x;
    if (i < N_NODES) rowptr[i] += bsum[blockIdx.x];
}

// ---------------- fp32 -> bf16 cast (x) ----------------
__global__ __launch_bounds__(256) void k_cast(const float* __restrict__ x,
                                              unsigned short* __restrict__ xb) {
    int idx = blockIdx.x * 256 + threadIdx.x;   // < N*32
    float4 v = ((const float4*)x)[idx];
    ushort4 o;
    o.x = f2bf(v.x); o.y = f2bf(v.y); o.z = f2bf(v.z); o.w = f2bf(v.w);
    ((ushort4*)xb)[idx] = o;
}

// ---------------- weight prep: WT[n][kcat] bf16, kcat = [Wr k | Wn k] -------
__global__ __launch_bounds__(256) void k_prepw(const float* __restrict__ Wr,
                                               const float* __restrict__ Wn,
                                               unsigned short* __restrict__ WT,
                                               int Nw) {
    int idx = blockIdx.x * 256 + threadIdx.x;   // < Nw*256
    int n = idx >> 8;
    int kc = idx & 255;
    float v = (kc < 128) ? Wr[kc * Nw + n] : Wn[(kc - 128) * Nw + n];
    WT[idx] = f2bf(v);
}

// weight prep layer2: WT2cat[n][k], n<64 -> Wr2 col n, n>=64 -> Wn2 col n-64
__global__ __launch_bounds__(256) void k_prepw2(const float* __restrict__ Wr,
                                                const float* __restrict__ Wn,
                                                unsigned short* __restrict__ WT) {
    int idx = blockIdx.x * 256 + threadIdx.x;   // < 128*128
    int n = idx >> 7;
    int k = idx & 127;
    float v = (n < 64) ? Wr[k * 64 + n] : Wn[k * 64 + (n - 64)];
    WT[n * 128 + k] = f2bf(v);
}

// ---------------- gather mean-aggregation (bf16, 128-dim) ------------------
__global__ __launch_bounds__(256) void k_gather(const uint2* __restrict__ hw2,
                                                const int* __restrict__ eidx,
                                                const int* __restrict__ rowptr,
                                                const int* __restrict__ deg,
                                                const float* __restrict__ invdeg,
                                                uint2* __restrict__ aggw2) {
    int node = blockIdx.x * 4 + (threadIdx.x >> 6);
    int lane = threadIdx.x & 63;
    int half = lane >> 5;
    int l = lane & 31;
    int start = rowptr[node];
    int cnt = deg[node];
    float a0 = 0.0f, a1 = 0.0f, a2 = 0.0f, a3 = 0.0f;
    int j = 0;
    for (; j + 8 <= cnt; j += 8) {
        int e = start + j + half * 4;
        int s0 = eidx[e], s1 = eidx[e + 1], s2 = eidx[e + 2], s3 = eidx[e + 3];
        uint2 u0 = hw2[s0 * 32 + l];
        uint2 u1 = hw2[s1 * 32 + l];
        uint2 u2 = hw2[s2 * 32 + l];
        uint2 u3 = hw2[s3 * 32 + l];
        a0 += bflo(u0.x) + bflo(u1.x) + bflo(u2.x) + bflo(u3.x);
        a1 += bfhi(u0.x) + bfhi(u1.x) + bfhi(u2.x) + bfhi(u3.x);
        a2 += bflo(u0.y) + bflo(u1.y) + bflo(u2.y) + bflo(u3.y);
        a3 += bfhi(u0.y) + bfhi(u1.y) + bfhi(u2.y) + bfhi(u3.y);
    }
    for (; j + 2 <= cnt; j += 2) {
        int s0 = eidx[start + j + half];
        uint2 u = hw2[s0 * 32 + l];
        a0 += bflo(u.x); a1 += bfhi(u.x);
        a2 += bflo(u.y); a3 += bfhi(u.y);
    }
    if (j < cnt && half == 0) {
        uint2 u = hw2[eidx[start + j] * 32 + l];
        a0 += bflo(u.x); a1 += bfhi(u.x);
        a2 += bflo(u.y); a3 += bfhi(u.y);
    }
    a0 += __shfl_xor(a0, 32);
    a1 += __shfl_xor(a1, 32);
    a2 += __shfl_xor(a2, 32);
    a3 += __shfl_xor(a3, 32);
    if (half == 0) {
        float id = invdeg[node];
        uint2 o;
        o.x = pack2(a0 * id, a1 * id);
        o.y = pack2(a2 * id, a3 * id);
        aggw2[node * 32 + l] = o;
    }
}

// ---------------- MFMA dual-GEMM + bias + LayerNorm + ReLU (K=256 -> 128) --
__global__ __launch_bounds__(256) void k_gemm_ln(
        const unsigned short* __restrict__ hb, const unsigned short* __restrict__ ab,
        const unsigned short* __restrict__ WT,
        const float* __restrict__ b, const float* __restrict__ g,
        const float* __restrict__ be, unsigned short* __restrict__ outb) {
    __shared__ unsigned short hl[32][136];
    __shared__ unsigned short al[32][136];
    __shared__ unsigned short bt[128][72];
    __shared__ float p1[2][32], p2[2][32];

    const int tid = threadIdx.x;
    const int lane = tid & 63;
    const int w = tid >> 6;
    const int quad = lane >> 4;
    const int l15 = lane & 15;
    const int rt = w >> 1;
    const int ch = w & 1;
    const int row0 = blockIdx.x * 32;

    #pragma unroll
    for (int t = 0; t < 2; ++t) {
        int idx = tid + t * 256;
        int r = idx >> 4;
        int c8 = idx & 15;
        *(float4*)&hl[r][c8 * 8] = ((const float4*)hb)[(size_t)(row0 + r) * 16 + c8];
        *(float4*)&al[r][c8 * 8] = ((const float4*)ab)[(size_t)(row0 + r) * 16 + c8];
    }

    f32x4 acc[4];
    #pragma unroll
    for (int t = 0; t < 4; ++t)
        #pragma unroll
        for (int r = 0; r < 4; ++r) acc[t][r] = 0.0f;

    #pragma unroll
    for (int kt = 0; kt < 4; ++kt) {
        __syncthreads();
        #pragma unroll
        for (int t = 0; t < 4; ++t) {
            int idx = tid + t * 256;
            int n = idx >> 3;
            int c8 = idx & 7;
            *(float4*)&bt[n][c8 * 8] = ((const float4*)WT)[n * 32 + kt * 8 + c8];
        }
        __syncthreads();
        #pragma unroll
        for (int ks = 0; ks < 2; ++ks) {
            const int ck = kt * 64 + ks * 32;
            const unsigned short* ap = (ck < 128)
                ? &hl[rt * 16 + l15][ck + quad * 8]
                : &al[rt * 16 + l15][ck - 128 + quad * 8];
            bf16x8 a = *(const bf16x8*)ap;
            #pragma unroll
            for (int t = 0; t < 4; ++t) {
                bf16x8 bb = *(const bf16x8*)&bt[ch * 64 + t * 16 + l15][ks * 32 + quad * 8];
                acc[t] = __builtin_amdgcn_mfma_f32_16x16x32_bf16(a, bb, acc[t], 0, 0, 0);
            }
        }
    }

    float bcol[4], gc[4], bec[4];
    #pragma unroll
    for (int t = 0; t < 4; ++t) {
        int col = ch * 64 + t * 16 + l15;
        bcol[t] = b[col]; gc[t] = g[col]; bec[t] = be[col];
    }
    float v[4][4];
    float s1[4], s2[4];
    #pragma unroll
    for (int r = 0; r < 4; ++r) { s1[r] = 0.0f; s2[r] = 0.0f; }
    #pragma unroll
    for (int t = 0; t < 4; ++t)
        #pragma unroll
        for (int r = 0; r < 4; ++r) {
            float x = acc[t][r] + bcol[t];
            v[t][r] = x;
            s1[r] += x;
            s2[r] += x * x;
        }
    #pragma unroll
    for (int m = 1; m <= 8; m <<= 1)
        #pragma unroll
        for (int r = 0; r < 4; ++r) {
            s1[r] += __shfl_xor(s1[r], m);
            s2[r] += __shfl_xor(s2[r], m);
        }
    if (l15 == 0) {
        #pragma unroll
        for (int r = 0; r < 4; ++r) {
            int rl = rt * 16 + quad * 4 + r;
            p1[ch][rl] = s1[r];
            p2[ch][rl] = s2[r];
        }
    }
    __syncthreads();
    #pragma unroll
    for (int r = 0; r < 4; ++r) {
        int rl = rt * 16 + quad * 4 + r;
        float S1 = p1[0][rl] + p1[1][rl];
        float S2 = p2[0][rl] + p2[1][rl];
        float mean = S1 * (1.0f / 128.0f);
        float var = S2 * (1.0f / 128.0f) - mean * mean;
        float rstd = rsqrtf(var + EPS);
        #pragma unroll
        for (int t = 0; t < 4; ++t) {
            float o = fmaxf((v[t][r] - mean) * rstd * gc[t] + bec[t], 0.0f);
            outb[(size_t)(row0 + rl) * 128 + ch * 64 + t * 16 + l15] = f2bf(o);
        }
    }
}

// ---------------- layer 2 GEMM: zy = h2 @ [Wr2|Wn2] (+b2 on z half) --------
__global__ __launch_bounds__(256) void k_gemm2(
        const unsigned short* __restrict__ hb, const unsigned short* __restrict__ WT,
        const float* __restrict__ b2, unsigned short* __restrict__ zyb) {
    __shared__ unsigned short hl[32][136];
    __shared__ unsigned short bt[128][136];

    const int tid = threadIdx.x;
    const int lane = tid & 63;
    const int w = tid >> 6;
    const int quad = lane >> 4;
    const int l15 = lane & 15;
    const int rt = w >> 1;
    const int ch = w & 1;
    const int row0 = blockIdx.x * 32;

    #pragma unroll
    for (int t = 0; t < 2; ++t) {
        int idx = tid + t * 256;
        int r = idx >> 4;
        int c8 = idx & 15;
        *(float4*)&hl[r][c8 * 8] = ((const float4*)hb)[(size_t)(row0 + r) * 16 + c8];
    }
    #pragma unroll
    for (int t = 0; t < 8; ++t) {
        int idx = tid + t * 256;
        int n = idx >> 4;
        int c8 = idx & 15;
        *(float4*)&bt[n][c8 * 8] = ((const float4*)WT)[n * 16 + c8];
    }
    __syncthreads();

    f32x4 acc[4];
    #pragma unroll
    for (int t = 0; t < 4; ++t)
        #pragma unroll
        for (int r = 0; r < 4; ++r) acc[t][r] = 0.0f;

    #pragma unroll
    for (int ks = 0; ks < 4; ++ks) {
        bf16x8 a = *(const bf16x8*)&hl[rt * 16 + l15][ks * 32 + quad * 8];
        #pragma unroll
        for (int t = 0; t < 4; ++t) {
            bf16x8 bb = *(const bf16x8*)&bt[ch * 64 + t * 16 + l15][ks * 32 + quad * 8];
            acc[t] = __builtin_amdgcn_mfma_f32_16x16x32_bf16(a, bb, acc[t], 0, 0, 0);
        }
    }

    #pragma unroll
    for (int t = 0; t < 4; ++t) {
        int col = ch * 64 + t * 16 + l15;
        float bc = (col < 64) ? b2[col] : 0.0f;
        #pragma unroll
        for (int r = 0; r < 4; ++r) {
            int rl = rt * 16 + quad * 4 + r;
            zyb[(size_t)(row0 + rl) * 128 + col] = f2bf(acc[t][r] + bc);
        }
    }
}

// ------- final: gather-mean y (64-dim) + z + log_softmax, fp32 out ---------
__global__ __launch_bounds__(256) void k_l2g(const unsigned* __restrict__ zyw,
                                             const int* __restrict__ eidx,
                                             const int* __restrict__ rowptr,
                                             const int* __restrict__ deg,
                                             const float* __restrict__ invdeg,
                                             float* __restrict__ out) {
    int node = blockIdx.x * 8 + (threadIdx.x >> 5);
    int l = threadIdx.x & 31;
    int start = rowptr[node];
    int cnt = deg[node];
    float ax = 0.0f, ay = 0.0f;
    int j = 0;
    for (; j + 4 <= cnt; j += 4) {
        int s0 = eidx[start + j];
        int s1 = eidx[start + j + 1];
        int s2 = eidx[start + j + 2];
        int s3 = eidx[start + j + 3];
        unsigned u0 = zyw[s0 * 64 + 32 + l];
        unsigned u1 = zyw[s1 * 64 + 32 + l];
        unsigned u2 = zyw[s2 * 64 + 32 + l];
        unsigned u3 = zyw[s3 * 64 + 32 + l];
        ax += bflo(u0) + bflo(u1) + bflo(u2) + bflo(u3);
        ay += bfhi(u0) + bfhi(u1) + bfhi(u2) + bfhi(u3);
    }
    for (; j < cnt; ++j) {
        unsigned u = zyw[eidx[start + j] * 64 + 32 + l];
        ax += bflo(u);
        ay += bfhi(u);
    }
    float id = invdeg[node];
    unsigned uz = zyw[node * 64 + l];
    float v0 = bflo(uz) + ax * id;
    float v1 = bfhi(uz) + ay * id;

    float m = fmaxf(v0, v1);
    #pragma unroll
    for (int msk = 1; msk <= 16; msk <<= 1) m = fmaxf(m, __shfl_xor(m, msk, 32));
    float s = __expf(v0 - m) + __expf(v1 - m);
    #pragma unroll
    for (int msk = 1; msk <= 16; msk <<= 1) s += __shfl_xor(s, msk, 32);
    float L = logf(s);
    float2 o;
    o.x = v0 - m - L;
    o.y = v1 - m - L;
    ((float2*)out)[(size_t)node * 32 + l] = o;
}

extern "C" void kernel_launch(void* const* d_in, const int* in_sizes, int n_in,
                              void* d_out, int out_size, void* d_ws, size_t ws_size,
                              hipStream_t stream) {
    const float* x   = (const float*)d_in[0];
    const int* esrc  = (const int*)d_in[1];
    const int* edst  = (const int*)d_in[2];
    const float* Wr0 = (const float*)d_in[3];
    const float* Wn0 = (const float*)d_in[4];
    const float* b0  = (const float*)d_in[5];
    const float* g0  = (const float*)d_in[6];
    const float* be0 = (const float*)d_in[7];
    const float* Wr1 = (const float*)d_in[8];
    const float* Wn1 = (const float*)d_in[9];
    const float* b1  = (const float*)d_in[10];
    const float* g1  = (const float*)d_in[11];
    const float* be1 = (const float*)d_in[12];
    const float* Wr2 = (const float*)d_in[13];
    const float* Wn2 = (const float*)d_in[14];
    const float* b2  = (const float*)d_in[15];
    float* out = (float*)d_out;

    char* p = (char*)d_ws;
    auto alloc = [&](size_t bytes) {
        void* r = (void*)p;
        p += (bytes + 255) & ~(size_t)255;
        return r;
    };
    int*   deg    = (int*)  alloc(N_NODES * 4);
    float* invdeg = (float*)alloc(N_NODES * 4);
    int*   rowptr = (int*)  alloc(N_NODES * 4);
    int*   bsum   = (int*)  alloc(NB * 4);
    int*   cntG   = (int*)  alloc(NR * NC * 4);
    int*   bsrc   = (int*)  alloc((size_t)N_EDGES * 4);
    int*   bdst   = (int*)  alloc((size_t)N_EDGES * 4);
    int*   eidx   = (int*)  alloc((size_t)N_EDGES * 4);
    unsigned short* xb   = (unsigned short*)alloc((size_t)N_NODES * 128 * 2); // also h2
    unsigned short* h1   = (unsigned short*)alloc((size_t)N_NODES * 128 * 2); // also zy
    unsigned short* aggb = (unsigned short*)alloc((size_t)N_NODES * 128 * 2);
    unsigned short* WT0  = (unsigned short*)alloc(128 * 256 * 2);
    unsigned short* WT1  = (unsigned short*)alloc(128 * 256 * 2);
    unsigned short* WT2  = (unsigned short*)alloc(128 * 128 * 2);

    // prep: cast x to bf16, transpose+cast weights
    k_cast<<<N_NODES * 32 / 256, 256, 0, stream>>>(x, xb);
    k_prepw<<<128, 256, 0, stream>>>(Wr0, Wn0, WT0, 128);
    k_prepw<<<128, 256, 0, stream>>>(Wr1, Wn1, WT1, 128);
    k_prepw2<<<64, 256, 0, stream>>>(Wr2, Wn2, WT2);

    // CSR build: atomic-free two-level counting sort
    k_count<<<NC, 256, 0, stream>>>(edst, cntG);
    k_scanA<<<1, 256, 0, stream>>>(cntG);
    k_bin<<<NC, 256, 0, stream>>>(esrc, edst, cntG, bsrc, bdst);
    k_nodec<<<NR, 256, 0, stream>>>(bdst, cntG, deg);
    k_invdeg<<<NB, 256, 0, stream>>>(deg, invdeg);
    k_scan1<<<NB, 256, 0, stream>>>(deg, rowptr, bsum);
    k_scan2<<<1, 512, 0, stream>>>(bsum);
    k_scan3<<<NB, 256, 0, stream>>>(rowptr, bsum);
    k_place<<<NR, 256, 0, stream>>>(bsrc, bdst, cntG, rowptr, eidx);

    // layer 0
    k_gather<<<N_NODES / 4, 256, 0, stream>>>((const uint2*)xb, eidx, rowptr, deg, invdeg, (uint2*)aggb);
    k_gemm_ln<<<N_NODES / 32, 256, 0, stream>>>(xb, aggb, WT0, b0, g0, be0, h1);

    // layer 1 (h2 goes back into xb's buffer)
    k_gather<<<N_NODES / 4, 256, 0, stream>>>((const uint2*)h1, eidx, rowptr, deg, invdeg, (uint2*)aggb);
    k_gemm_ln<<<N_NODES / 32, 256, 0, stream>>>(h1, aggb, WT1, b1, g1, be1, xb);

    // layer 2: zy = h2 @ [Wr2|Wn2] (+b2), then gather y-half + log_softmax
    k_gemm2<<<N_NODES / 32, 256, 0, stream>>>(xb, WT2, b2, h1);
    k_l2g<<<N_NODES / 8, 256, 0, stream>>>((const unsigned*)h1, eidx, rowptr, deg, invdeg, out);
}

// Round 6
// 449.745 us; speedup vs baseline: 19.4740x; 1.0326x over previous
//
#include <hip/hip_runtime.h>
#include <math.h>

#define N_NODES 100000
#define N_EDGES 1600000
#define EPS 1e-5f
#define NB 391              // ceil(100000/256) scan blocks
#define NC 256              // edge chunks
#define CHUNK 6250          // N_EDGES / NC
#define NR 98               // ceil(100000/1024) dst ranges
#define RSZ 1024            // nodes per range

typedef __bf16 bf16x8 __attribute__((ext_vector_type(8)));
typedef float f32x4 __attribute__((ext_vector_type(4)));

__device__ inline unsigned short f2bf(float f) {    // RNE, finite inputs
    unsigned u = __float_as_uint(f);
    unsigned r = u + 0x7fffu + ((u >> 16) & 1u);
    return (unsigned short)(r >> 16);
}
__device__ inline float bflo(unsigned u) { return __uint_as_float(u << 16); }
__device__ inline float bfhi(unsigned u) { return __uint_as_float(u & 0xffff0000u); }
__device__ inline unsigned pack2(float lo, float hi) {
    return (unsigned)f2bf(lo) | ((unsigned)f2bf(hi) << 16);
}

// ============ CSR build, no global atomics ============
__global__ __launch_bounds__(256) void k_count(const int* __restrict__ dst,
                                               int* __restrict__ cntG) {
    __shared__ int hist[NR];
    int t = threadIdx.x, c = blockIdx.x;
    for (int i = t; i < NR; i += 256) hist[i] = 0;
    __syncthreads();
    int base = c * CHUNK;
    for (int i = base + t; i < base + CHUNK; i += 256)
        atomicAdd(&hist[dst[i] >> 10], 1);
    __syncthreads();
    for (int i = t; i < NR; i += 256) cntG[i * NC + c] = hist[i];
}

__global__ __launch_bounds__(256) void k_scanA(int* __restrict__ cntG) {
    __shared__ int ts[256];
    int t = threadIdx.x;
    const int PER = (NR * NC) / 256;   // 98
    int s = 0;
    for (int i = 0; i < PER; ++i) s += cntG[t * PER + i];
    ts[t] = s;
    __syncthreads();
    #pragma unroll
    for (int off = 1; off < 256; off <<= 1) {
        int y = 0;
        if (t >= off) y = ts[t - off];
        __syncthreads();
        if (t >= off) ts[t] += y;
        __syncthreads();
    }
    int run = ts[t] - s;               // exclusive
    for (int i = 0; i < PER; ++i) {
        int v = cntG[t * PER + i];
        cntG[t * PER + i] = run;
        run += v;
    }
}

__global__ __launch_bounds__(256) void k_bin(const int* __restrict__ src,
                                             const int* __restrict__ dst,
                                             const int* __restrict__ baseG,
                                             int* __restrict__ bsrc,
                                             int* __restrict__ bdst) {
    __shared__ int cur[NR];
    int t = threadIdx.x, c = blockIdx.x;
    for (int i = t; i < NR; i += 256) cur[i] = baseG[i * NC + c];
    __syncthreads();
    int base = c * CHUNK;
    for (int i = base + t; i < base + CHUNK; i += 256) {
        int d = dst[i];
        int s = src[i];
        int p = atomicAdd(&cur[d >> 10], 1);
        bsrc[p] = s;
        bdst[p] = d;
    }
}

// Pass 4: per-range node histogram -> deg + invdeg (no global atomics)
__global__ __launch_bounds__(256) void k_nodec(const int* __restrict__ bdst,
                                               const int* __restrict__ baseG,
                                               int* __restrict__ deg,
                                               float* __restrict__ invdeg) {
    __shared__ int hist[RSZ];
    int r = blockIdx.x, t = threadIdx.x;
    for (int i = t; i < RSZ; i += 256) hist[i] = 0;
    __syncthreads();
    int s0 = baseG[r * NC];
    int s1 = (r == NR - 1) ? N_EDGES : baseG[(r + 1) * NC];
    int nbase = r << 10;
    for (int i = s0 + t; i < s1; i += 256)
        atomicAdd(&hist[bdst[i] - nbase], 1);
    __syncthreads();
    for (int i = t; i < RSZ && nbase + i < N_NODES; i += 256) {
        int d = hist[i];
        deg[nbase + i] = d;
        invdeg[nbase + i] = 1.0f / fmaxf((float)d, 1.0f);
    }
}

__global__ __launch_bounds__(256) void k_place(const int* __restrict__ bsrc,
                                               const int* __restrict__ bdst,
                                               const int* __restrict__ baseG,
                                               const int* __restrict__ rowptr,
                                               int* __restrict__ eidx) {
    __shared__ int cur[RSZ];
    int r = blockIdx.x, t = threadIdx.x;
    int nbase = r << 10;
    for (int i = t; i < RSZ; i += 256)
        cur[i] = (nbase + i < N_NODES) ? rowptr[nbase + i] : 0;
    __syncthreads();
    int s0 = baseG[r * NC];
    int s1 = (r == NR - 1) ? N_EDGES : baseG[(r + 1) * NC];
    for (int i = s0 + t; i < s1; i += 256) {
        int d = bdst[i];
        int s = bsrc[i];
        int p = atomicAdd(&cur[d - nbase], 1);
        eidx[p] = s;
    }
}

// ============ node-level rowptr scan ============
__global__ __launch_bounds__(256) void k_scan1(const int* __restrict__ deg,
                                               int* __restrict__ rowptr,
                                               int* __restrict__ bsum) {
    __shared__ int tmp[256];
    int t = threadIdx.x;
    int i = blockIdx.x * 256 + t;
    int v = (i < N_NODES) ? deg[i] : 0;
    tmp[t] = v;
    __syncthreads();
    #pragma unroll
    for (int off = 1; off < 256; off <<= 1) {
        int y = 0;
        if (t >= off) y = tmp[t - off];
        __syncthreads();
        if (t >= off) tmp[t] += y;
        __syncthreads();
    }
    if (i < N_NODES) rowptr[i] = tmp[t] - v;
    if (t == 255) bsum[blockIdx.x] = tmp[t];
}

__global__ __launch_bounds__(512) void k_scan2(int* __restrict__ bsum) {
    __shared__ int tmp[512];
    int t = threadIdx.x;
    int v = (t < NB) ? bsum[t] : 0;
    tmp[t] = v;
    __syncthreads();
    #pragma unroll
    for (int off = 1; off < 512; off <<= 1) {
        int y = 0;
        if (t >= off) y = tmp[t - off];
        __syncthreads();
        if (t >= off) tmp[t] += y;
        __syncthreads();
    }
    if (t < NB) bsum[t] = tmp[t] - v;
}

__global__ __launch_bounds__(256) void k_scan3(int* __restrict__ rowptr,
                                               const int* __restrict__ bsum) {
    int i = blockIdx.x * 256 + threadIdx.x;
    if (i < N_NODES) rowptr[i] += bsum[blockIdx.x];
}

// ---------------- fp32 -> bf16 cast (x) ----------------
__global__ __launch_bounds__(256) void k_cast(const float* __restrict__ x,
                                              unsigned short* __restrict__ xb) {
    int idx = blockIdx.x * 256 + threadIdx.x;   // < N*32
    float4 v = ((const float4*)x)[idx];
    ushort4 o;
    o.x = f2bf(v.x); o.y = f2bf(v.y); o.z = f2bf(v.z); o.w = f2bf(v.w);
    ((ushort4*)xb)[idx] = o;
}

// ---------------- weight prep ----------------
__global__ __launch_bounds__(256) void k_prepw(const float* __restrict__ Wr,
                                               const float* __restrict__ Wn,
                                               unsigned short* __restrict__ WT,
                                               int Nw) {
    int idx = blockIdx.x * 256 + threadIdx.x;   // < Nw*256
    int n = idx >> 8;
    int kc = idx & 255;
    float v = (kc < 128) ? Wr[kc * Nw + n] : Wn[(kc - 128) * Nw + n];
    WT[idx] = f2bf(v);
}

__global__ __launch_bounds__(256) void k_prepw2(const float* __restrict__ Wr,
                                                const float* __restrict__ Wn,
                                                unsigned short* __restrict__ WT) {
    int idx = blockIdx.x * 256 + threadIdx.x;   // < 128*128
    int n = idx >> 7;
    int k = idx & 127;
    float v = (n < 64) ? Wr[k * 64 + n] : Wn[k * 64 + (n - 64)];
    WT[n * 128 + k] = f2bf(v);
}

// ---------------- gather mean-aggregation (bf16, 128-dim) ------------------
// One wave per node. Row = 256B = 16 lanes x uint4; sub = lane>>4 picks the
// edge, so one wave-wide dwordx4 load fetches 4 edge rows (1 KB). 2 loads in
// flight per iter (8 edges). 4-way cross-sub reduce (xor 16,32) at the end.
__global__ __launch_bounds__(256) void k_gather(const uint4* __restrict__ hw4,
                                                const int* __restrict__ eidx,
                                                const int* __restrict__ rowptr,
                                                const int* __restrict__ deg,
                                                const float* __restrict__ invdeg,
                                                uint4* __restrict__ aggw4) {
    int node = blockIdx.x * 4 + (threadIdx.x >> 6);
    int lane = threadIdx.x & 63;
    int sub = lane >> 4;       // edge subgroup 0..3
    int l = lane & 15;         // 16B feature chunk
    int start = rowptr[node];
    int cnt = deg[node];
    float a[8];
    #pragma unroll
    for (int i = 0; i < 8; ++i) a[i] = 0.0f;

    int j = 0;
    for (; j + 8 <= cnt; j += 8) {
        int s0 = eidx[start + j + sub];
        int s1 = eidx[start + j + 4 + sub];
        uint4 u0 = hw4[(size_t)s0 * 16 + l];
        uint4 u1 = hw4[(size_t)s1 * 16 + l];
        a[0] += bflo(u0.x); a[1] += bfhi(u0.x);
        a[2] += bflo(u0.y); a[3] += bfhi(u0.y);
        a[4] += bflo(u0.z); a[5] += bfhi(u0.z);
        a[6] += bflo(u0.w); a[7] += bfhi(u0.w);
        a[0] += bflo(u1.x); a[1] += bfhi(u1.x);
        a[2] += bflo(u1.y); a[3] += bfhi(u1.y);
        a[4] += bflo(u1.z); a[5] += bfhi(u1.z);
        a[6] += bflo(u1.w); a[7] += bfhi(u1.w);
    }
    if (j + 4 <= cnt) {
        int s0 = eidx[start + j + sub];
        uint4 u0 = hw4[(size_t)s0 * 16 + l];
        a[0] += bflo(u0.x); a[1] += bfhi(u0.x);
        a[2] += bflo(u0.y); a[3] += bfhi(u0.y);
        a[4] += bflo(u0.z); a[5] += bfhi(u0.z);
        a[6] += bflo(u0.w); a[7] += bfhi(u0.w);
        j += 4;
    }
    int rem = cnt - j;          // 0..3
    if (sub < rem) {
        uint4 u0 = hw4[(size_t)eidx[start + j + sub] * 16 + l];
        a[0] += bflo(u0.x); a[1] += bfhi(u0.x);
        a[2] += bflo(u0.y); a[3] += bfhi(u0.y);
        a[4] += bflo(u0.z); a[5] += bfhi(u0.z);
        a[6] += bflo(u0.w); a[7] += bfhi(u0.w);
    }
    #pragma unroll
    for (int i = 0; i < 8; ++i) {
        a[i] += __shfl_xor(a[i], 16);
        a[i] += __shfl_xor(a[i], 32);
    }
    if (lane < 16) {
        float id = invdeg[node];
        uint4 o;
        o.x = pack2(a[0] * id, a[1] * id);
        o.y = pack2(a[2] * id, a[3] * id);
        o.z = pack2(a[4] * id, a[5] * id);
        o.w = pack2(a[6] * id, a[7] * id);
        aggw4[(size_t)node * 16 + l] = o;
    }
}

// ---------------- MFMA dual-GEMM + bias + LayerNorm + ReLU (K=256 -> 128) --
__global__ __launch_bounds__(256) void k_gemm_ln(
        const unsigned short* __restrict__ hb, const unsigned short* __restrict__ ab,
        const unsigned short* __restrict__ WT,
        const float* __restrict__ b, const float* __restrict__ g,
        const float* __restrict__ be, unsigned short* __restrict__ outb) {
    __shared__ unsigned short hl[32][136];
    __shared__ unsigned short al[32][136];
    __shared__ unsigned short bt[128][72];
    __shared__ float p1[2][32], p2[2][32];

    const int tid = threadIdx.x;
    const int lane = tid & 63;
    const int w = tid >> 6;
    const int quad = lane >> 4;
    const int l15 = lane & 15;
    const int rt = w >> 1;
    const int ch = w & 1;
    const int row0 = blockIdx.x * 32;

    #pragma unroll
    for (int t = 0; t < 2; ++t) {
        int idx = tid + t * 256;
        int r = idx >> 4;
        int c8 = idx & 15;
        *(float4*)&hl[r][c8 * 8] = ((const float4*)hb)[(size_t)(row0 + r) * 16 + c8];
        *(float4*)&al[r][c8 * 8] = ((const float4*)ab)[(size_t)(row0 + r) * 16 + c8];
    }

    f32x4 acc[4];
    #pragma unroll
    for (int t = 0; t < 4; ++t)
        #pragma unroll
        for (int r = 0; r < 4; ++r) acc[t][r] = 0.0f;

    #pragma unroll
    for (int kt = 0; kt < 4; ++kt) {
        __syncthreads();
        #pragma unroll
        for (int t = 0; t < 4; ++t) {
            int idx = tid + t * 256;
            int n = idx >> 3;
            int c8 = idx & 7;
            *(float4*)&bt[n][c8 * 8] = ((const float4*)WT)[n * 32 + kt * 8 + c8];
        }
        __syncthreads();
        #pragma unroll
        for (int ks = 0; ks < 2; ++ks) {
            const int ck = kt * 64 + ks * 32;
            const unsigned short* ap = (ck < 128)
                ? &hl[rt * 16 + l15][ck + quad * 8]
                : &al[rt * 16 + l15][ck - 128 + quad * 8];
            bf16x8 a = *(const bf16x8*)ap;
            #pragma unroll
            for (int t = 0; t < 4; ++t) {
                bf16x8 bb = *(const bf16x8*)&bt[ch * 64 + t * 16 + l15][ks * 32 + quad * 8];
                acc[t] = __builtin_amdgcn_mfma_f32_16x16x32_bf16(a, bb, acc[t], 0, 0, 0);
            }
        }
    }

    float bcol[4], gc[4], bec[4];
    #pragma unroll
    for (int t = 0; t < 4; ++t) {
        int col = ch * 64 + t * 16 + l15;
        bcol[t] = b[col]; gc[t] = g[col]; bec[t] = be[col];
    }
    float v[4][4];
    float s1[4], s2[4];
    #pragma unroll
    for (int r = 0; r < 4; ++r) { s1[r] = 0.0f; s2[r] = 0.0f; }
    #pragma unroll
    for (int t = 0; t < 4; ++t)
        #pragma unroll
        for (int r = 0; r < 4; ++r) {
            float x = acc[t][r] + bcol[t];
            v[t][r] = x;
            s1[r] += x;
            s2[r] += x * x;
        }
    #pragma unroll
    for (int m = 1; m <= 8; m <<= 1)
        #pragma unroll
        for (int r = 0; r < 4; ++r) {
            s1[r] += __shfl_xor(s1[r], m);
            s2[r] += __shfl_xor(s2[r], m);
        }
    if (l15 == 0) {
        #pragma unroll
        for (int r = 0; r < 4; ++r) {
            int rl = rt * 16 + quad * 4 + r;
            p1[ch][rl] = s1[r];
            p2[ch][rl] = s2[r];
        }
    }
    __syncthreads();
    #pragma unroll
    for (int r = 0; r < 4; ++r) {
        int rl = rt * 16 + quad * 4 + r;
        float S1 = p1[0][rl] + p1[1][rl];
        float S2 = p2[0][rl] + p2[1][rl];
        float mean = S1 * (1.0f / 128.0f);
        float var = S2 * (1.0f / 128.0f) - mean * mean;
        float rstd = rsqrtf(var + EPS);
        #pragma unroll
        for (int t = 0; t < 4; ++t) {
            float o = fmaxf((v[t][r] - mean) * rstd * gc[t] + bec[t], 0.0f);
            outb[(size_t)(row0 + rl) * 128 + ch * 64 + t * 16 + l15] = f2bf(o);
        }
    }
}

// ---------------- layer 2 GEMM: zy = h2 @ [Wr2|Wn2] (+b2 on z half) --------
__global__ __launch_bounds__(256) void k_gemm2(
        const unsigned short* __restrict__ hb, const unsigned short* __restrict__ WT,
        const float* __restrict__ b2, unsigned short* __restrict__ zyb) {
    __shared__ unsigned short hl[32][136];
    __shared__ unsigned short bt[128][136];

    const int tid = threadIdx.x;
    const int lane = tid & 63;
    const int w = tid >> 6;
    const int quad = lane >> 4;
    const int l15 = lane & 15;
    const int rt = w >> 1;
    const int ch = w & 1;
    const int row0 = blockIdx.x * 32;

    #pragma unroll
    for (int t = 0; t < 2; ++t) {
        int idx = tid + t * 256;
        int r = idx >> 4;
        int c8 = idx & 15;
        *(float4*)&hl[r][c8 * 8] = ((const float4*)hb)[(size_t)(row0 + r) * 16 + c8];
    }
    #pragma unroll
    for (int t = 0; t < 8; ++t) {
        int idx = tid + t * 256;
        int n = idx >> 4;
        int c8 = idx & 15;
        *(float4*)&bt[n][c8 * 8] = ((const float4*)WT)[n * 16 + c8];
    }
    __syncthreads();

    f32x4 acc[4];
    #pragma unroll
    for (int t = 0; t < 4; ++t)
        #pragma unroll
        for (int r = 0; r < 4; ++r) acc[t][r] = 0.0f;

    #pragma unroll
    for (int ks = 0; ks < 4; ++ks) {
        bf16x8 a = *(const bf16x8*)&hl[rt * 16 + l15][ks * 32 + quad * 8];
        #pragma unroll
        for (int t = 0; t < 4; ++t) {
            bf16x8 bb = *(const bf16x8*)&bt[ch * 64 + t * 16 + l15][ks * 32 + quad * 8];
            acc[t] = __builtin_amdgcn_mfma_f32_16x16x32_bf16(a, bb, acc[t], 0, 0, 0);
        }
    }

    #pragma unroll
    for (int t = 0; t < 4; ++t) {
        int col = ch * 64 + t * 16 + l15;
        float bc = (col < 64) ? b2[col] : 0.0f;
        #pragma unroll
        for (int r = 0; r < 4; ++r) {
            int rl = rt * 16 + quad * 4 + r;
            zyb[(size_t)(row0 + rl) * 128 + col] = f2bf(acc[t][r] + bc);
        }
    }
}

// ------- final: gather-mean y (64-dim) + z + log_softmax, fp32 out ---------
// 32-lane group per node; y-row = 128B = 8 lanes x uint4; sub = lane>>3 picks
// the edge (4 edges per wave-wide load). Reduce xor 8,16; lanes 0-7 epilogue.
__global__ __launch_bounds__(256) void k_l2g(const uint4* __restrict__ zy4,
                                             const int* __restrict__ eidx,
                                             const int* __restrict__ rowptr,
                                             const int* __restrict__ deg,
                                             const float* __restrict__ invdeg,
                                             float* __restrict__ out) {
    int node = blockIdx.x * 8 + (threadIdx.x >> 5);
    int lane = threadIdx.x & 31;
    int sub = lane >> 3;       // edge subgroup 0..3
    int l = lane & 7;          // 16B chunk of the y half
    int start = rowptr[node];
    int cnt = deg[node];
    float a[8];
    #pragma unroll
    for (int i = 0; i < 8; ++i) a[i] = 0.0f;

    int j = 0;
    for (; j + 8 <= cnt; j += 8) {
        int s0 = eidx[start + j + sub];
        int s1 = eidx[start + j + 4 + sub];
        uint4 u0 = zy4[(size_t)s0 * 16 + 8 + l];
        uint4 u1 = zy4[(size_t)s1 * 16 + 8 + l];
        a[0] += bflo(u0.x); a[1] += bfhi(u0.x);
        a[2] += bflo(u0.y); a[3] += bfhi(u0.y);
        a[4] += bflo(u0.z); a[5] += bfhi(u0.z);
        a[6] += bflo(u0.w); a[7] += bfhi(u0.w);
        a[0] += bflo(u1.x); a[1] += bfhi(u1.x);
        a[2] += bflo(u1.y); a[3] += bfhi(u1.y);
        a[4] += bflo(u1.z); a[5] += bfhi(u1.z);
        a[6] += bflo(u1.w); a[7] += bfhi(u1.w);
    }
    if (j + 4 <= cnt) {
        int s0 = eidx[start + j + sub];
        uint4 u0 = zy4[(size_t)s0 * 16 + 8 + l];
        a[0] += bflo(u0.x); a[1] += bfhi(u0.x);
        a[2] += bflo(u0.y); a[3] += bfhi(u0.y);
        a[4] += bflo(u0.z); a[5] += bfhi(u0.z);
        a[6] += bflo(u0.w); a[7] += bfhi(u0.w);
        j += 4;
    }
    int rem = cnt - j;
    if (sub < rem) {
        uint4 u0 = zy4[(size_t)eidx[start + j + sub] * 16 + 8 + l];
        a[0] += bflo(u0.x); a[1] += bfhi(u0.x);
        a[2] += bflo(u0.y); a[3] += bfhi(u0.y);
        a[4] += bflo(u0.z); a[5] += bfhi(u0.z);
        a[6] += bflo(u0.w); a[7] += bfhi(u0.w);
    }
    #pragma unroll
    for (int i = 0; i < 8; ++i) {
        a[i] += __shfl_xor(a[i], 8);
        a[i] += __shfl_xor(a[i], 16);
    }

    // lanes 0-7: v = z + mean(y); log_softmax over 64 vals (8 lanes x 8)
    float id = invdeg[node];
    uint4 uz = zy4[(size_t)node * 16 + l];     // z chunk (valid for l<8 lanes)
    float v[8];
    v[0] = bflo(uz.x) + a[0] * id; v[1] = bfhi(uz.x) + a[1] * id;
    v[2] = bflo(uz.y) + a[2] * id; v[3] = bfhi(uz.y) + a[3] * id;
    v[4] = bflo(uz.z) + a[4] * id; v[5] = bfhi(uz.z) + a[5] * id;
    v[6] = bflo(uz.w) + a[6] * id; v[7] = bfhi(uz.w) + a[7] * id;

    float m = v[0];
    #pragma unroll
    for (int i = 1; i < 8; ++i) m = fmaxf(m, v[i]);
    #pragma unroll
    for (int msk = 1; msk <= 4; msk <<= 1) m = fmaxf(m, __shfl_xor(m, msk));
    float s = 0.0f;
    #pragma unroll
    for (int i = 0; i < 8; ++i) s += __expf(v[i] - m);
    #pragma unroll
    for (int msk = 1; msk <= 4; msk <<= 1) s += __shfl_xor(s, msk);
    if (sub == 0) {
        float L = m + logf(s);
        float4 o0, o1;
        o0.x = v[0] - L; o0.y = v[1] - L; o0.z = v[2] - L; o0.w = v[3] - L;
        o1.x = v[4] - L; o1.y = v[5] - L; o1.z = v[6] - L; o1.w = v[7] - L;
        ((float4*)out)[(size_t)node * 16 + l * 2] = o0;
        ((float4*)out)[(size_t)node * 16 + l * 2 + 1] = o1;
    }
}

extern "C" void kernel_launch(void* const* d_in, const int* in_sizes, int n_in,
                              void* d_out, int out_size, void* d_ws, size_t ws_size,
                              hipStream_t stream) {
    const float* x   = (const float*)d_in[0];
    const int* esrc  = (const int*)d_in[1];
    const int* edst  = (const int*)d_in[2];
    const float* Wr0 = (const float*)d_in[3];
    const float* Wn0 = (const float*)d_in[4];
    const float* b0  = (const float*)d_in[5];
    const float* g0  = (const float*)d_in[6];
    const float* be0 = (const float*)d_in[7];
    const float* Wr1 = (const float*)d_in[8];
    const float* Wn1 = (const float*)d_in[9];
    const float* b1  = (const float*)d_in[10];
    const float* g1  = (const float*)d_in[11];
    const float* be1 = (const float*)d_in[12];
    const float* Wr2 = (const float*)d_in[13];
    const float* Wn2 = (const float*)d_in[14];
    const float* b2  = (const float*)d_in[15];
    float* out = (float*)d_out;

    char* p = (char*)d_ws;
    auto alloc = [&](size_t bytes) {
        void* r = (void*)p;
        p += (bytes + 255) & ~(size_t)255;
        return r;
    };
    int*   deg    = (int*)  alloc(N_NODES * 4);
    float* invdeg = (float*)alloc(N_NODES * 4);
    int*   rowptr = (int*)  alloc(N_NODES * 4);
    int*   bsum   = (int*)  alloc(NB * 4);
    int*   cntG   = (int*)  alloc(NR * NC * 4);
    int*   bsrc   = (int*)  alloc((size_t)N_EDGES * 4);
    int*   bdst   = (int*)  alloc((size_t)N_EDGES * 4);
    int*   eidx   = (int*)  alloc((size_t)N_EDGES * 4);
    unsigned short* xb   = (unsigned short*)alloc((size_t)N_NODES * 128 * 2); // also h2
    unsigned short* h1   = (unsigned short*)alloc((size_t)N_NODES * 128 * 2); // also zy
    unsigned short* aggb = (unsigned short*)alloc((size_t)N_NODES * 128 * 2);
    unsigned short* WT0  = (unsigned short*)alloc(128 * 256 * 2);
    unsigned short* WT1  = (unsigned short*)alloc(128 * 256 * 2);
    unsigned short* WT2  = (unsigned short*)alloc(128 * 128 * 2);

    // prep: cast x to bf16, transpose+cast weights
    k_cast<<<N_NODES * 32 / 256, 256, 0, stream>>>(x, xb);
    k_prepw<<<128, 256, 0, stream>>>(Wr0, Wn0, WT0, 128);
    k_prepw<<<128, 256, 0, stream>>>(Wr1, Wn1, WT1, 128);
    k_prepw2<<<64, 256, 0, stream>>>(Wr2, Wn2, WT2);

    // CSR build: atomic-free two-level counting sort
    k_count<<<NC, 256, 0, stream>>>(edst, cntG);
    k_scanA<<<1, 256, 0, stream>>>(cntG);
    k_bin<<<NC, 256, 0, stream>>>(esrc, edst, cntG, bsrc, bdst);
    k_nodec<<<NR, 256, 0, stream>>>(bdst, cntG, deg, invdeg);
    k_scan1<<<NB, 256, 0, stream>>>(deg, rowptr, bsum);
    k_scan2<<<1, 512, 0, stream>>>(bsum);
    k_scan3<<<NB, 256, 0, stream>>>(rowptr, bsum);
    k_place<<<NR, 256, 0, stream>>>(bsrc, bdst, cntG, rowptr, eidx);

    // layer 0
    k_gather<<<N_NODES / 4, 256, 0, stream>>>((const uint4*)xb, eidx, rowptr, deg, invdeg, (uint4*)aggb);
    k_gemm_ln<<<N_NODES / 32, 256, 0, stream>>>(xb, aggb, WT0, b0, g0, be0, h1);

    // layer 1 (h2 goes back into xb's buffer)
    k_gather<<<N_NODES / 4, 256, 0, stream>>>((const uint4*)h1, eidx, rowptr, deg, invdeg, (uint4*)aggb);
    k_gemm_ln<<<N_NODES / 32, 256, 0, stream>>>(h1, aggb, WT1, b1, g1, be1, xb);

    // layer 2: zy = h2 @ [Wr2|Wn2] (+b2), then gather y-half + log_softmax
    k_gemm2<<<N_NODES / 32, 256, 0, stream>>>(xb, WT2, b2, h1);
    k_l2g<<<N_NODES / 8, 256, 0, stream>>>((const uint4*)h1, eidx, rowptr, deg, invdeg, out);
}